// Round 6
// baseline (501.318 us; speedup 1.0000x reference)
//
#include <hip/hip_runtime.h>
#include <math.h>

// DeepSeekV3 MLA forward, MI355X gfx950.
// I/O fp32; internal math bf16 MFMA.
// Flash v6: 128-query tiles (32 q/wave as 2x16), double-buffered K/V staging with
//           counted vmcnt(10) (loads stay in flight across barriers), balanced pairs
//           {t,15-t}, XCD-local bh, no-max softmax, l via ones-B-fragment MFMA.
// GEMMs r7 (measured win): global_load_lds(16B) staging, XOR-swizzled unit map,
//           XCD-chunked block swizzle. 128x128, BK=32.
// B=2 S=2048 D=2048 H=16 NOPE=128 ROPE=64 DV=128 DQK=192 QLR=1536 KVLR=512

typedef unsigned short u16;
typedef __attribute__((ext_vector_type(8))) __bf16 bf16x8;
typedef __attribute__((ext_vector_type(4))) float f32x4;

#define DEV static __device__ __forceinline__

DEV float b2f(u16 v) { return __uint_as_float(((unsigned int)v) << 16); }
DEV u16 f2b(float f) {
  unsigned int u = __float_as_uint(f);
  u += 0x7fffu + ((u >> 16) & 1u);   // round-to-nearest-even
  return (u16)(u >> 16);
}

DEV float waveReduceSum(float v) {
  #pragma unroll
  for (int o = 32; o > 0; o >>= 1) v += __shfl_down(v, o, 64);
  return v;
}

// async global->LDS, 16B per lane; LDS dest = wave-uniform base + lane*16
DEV void gld16(const u16* g, u16* l) {
  __builtin_amdgcn_global_load_lds((const __attribute__((address_space(1))) void*)g,
                                   (__attribute__((address_space(3))) void*)l, 16, 0, 0);
}

// ---------------- convert fp32 -> bf16 (flat) ----------------
__global__ __launch_bounds__(256)
void cvt_f32_bf16(const float* __restrict__ in, u16* __restrict__ out, int n4) {
  int i = blockIdx.x * 256 + threadIdx.x;
  if (i < n4) {
    float4 v = reinterpret_cast<const float4*>(in)[i];
    ushort4 o;
    o.x = f2b(v.x); o.y = f2b(v.y); o.z = f2b(v.z); o.w = f2b(v.w);
    reinterpret_cast<ushort4*>(out)[i] = o;
  }
}

// ---------------- transpose+convert: in f32 [R][C] -> out bf16 [C][R] ----------------
__global__ __launch_bounds__(256)
void transpose_f32_bf16(const float* __restrict__ in, u16* __restrict__ out, int R, int C) {
  __shared__ u16 tile[32][33];
  int c0 = blockIdx.x * 32, r0 = blockIdx.y * 32;
  for (int i = threadIdx.y; i < 32; i += 8)
    tile[i][threadIdx.x] = f2b(in[(size_t)(r0 + i) * C + c0 + threadIdx.x]);
  __syncthreads();
  for (int i = threadIdx.y; i < 32; i += 8)
    out[(size_t)(c0 + i) * R + r0 + threadIdx.x] = tile[threadIdx.x][i];
}

// ---------------- MFMA bt-GEMM: C[M][N] = A[M][K] * BT[N][K]^T ----------------
// 128x128 tile, 4 waves, BK=32.
// LDS unit map (16B units): u = row*4 + (kq ^ ((row>>1)&3)), row 0..127, kq 0..3.
// Staging: global_load_lds 16B/lane, dest = wave-uniform chunk base (linear),
//   per-lane source decoded from u = jb + lane: row = u>>2, kq = (u&3)^((u>>3)&3).
//   -> 4 consecutive lanes read the same row's 4 K-octets (64B segment, permuted).
// Fragment read: unit (row<<2)|(q^((row>>1)&3)) -> 2-way bank aliasing (free).
// XCD swizzle: contiguous row-major tile chunk per XCD.
template<int OUT_BF16>
__global__ __launch_bounds__(256)
void gemm_bt(const u16* __restrict__ A, const u16* __restrict__ BT, void* __restrict__ Cp,
             int M, int N, int K) {
  __shared__ __attribute__((aligned(16))) u16 As[4096];
  __shared__ __attribute__((aligned(16))) u16 Bs[4096];
  const int tid = threadIdx.x;
  const int lane = tid & 63;
  const int wave = tid >> 6;
  const int wm = (wave >> 1) * 64;
  const int wn = (wave & 1) * 64;
  const int q = lane >> 4;
  const int l16 = lane & 15;

  // XCD-chunked bijective swizzle: XCD k = (orig%8) gets work tiles [k*cpx, (k+1)*cpx)
  const int gx = gridDim.x;
  const int nwg = gx * gridDim.y;
  const int orig = blockIdx.y * gx + blockIdx.x;
  const int cpx = nwg >> 3;
  const int swz = (orig & 7) * cpx + (orig >> 3);
  const int bm = (swz / gx) * 128;
  const int bn = (swz % gx) * 128;

  f32x4 zero = {0.f, 0.f, 0.f, 0.f};
  f32x4 acc[4][4];
  #pragma unroll
  for (int i = 0; i < 4; i++)
    #pragma unroll
    for (int j = 0; j < 4; j++) acc[i][j] = zero;

  for (int k0 = 0; k0 < K; k0 += 32) {
    #pragma unroll
    for (int i = 0; i < 2; i++) {
      int jb = i * 256 + wave * 64;      // chunk base, 16B units (wave-uniform)
      int u = jb + lane;
      int row = u >> 2;
      int kq = (u & 3) ^ ((u >> 3) & 3);
      gld16(A + (size_t)(bm + row) * K + k0 + kq * 8, As + jb * 8);
      int rB = bn + row;
      if (rB >= N) rB = N - 1;           // clamp: finite garbage, cols >= N never stored
      gld16(BT + (size_t)rB * K + k0 + kq * 8, Bs + jb * 8);
    }
    __syncthreads();   // vmcnt(0) drained before barrier: staging visible
    bf16x8 af[4], bfr[4];
    #pragma unroll
    for (int t = 0; t < 4; t++) {
      int rowA = wm + t * 16 + l16;
      int rowB = wn + t * 16 + l16;
      int uA = (rowA << 2) | (q ^ ((rowA >> 1) & 3));
      int uB = (rowB << 2) | (q ^ ((rowB >> 1) & 3));
      af[t]  = *reinterpret_cast<const bf16x8*>(As + uA * 8);
      bfr[t] = *reinterpret_cast<const bf16x8*>(Bs + uB * 8);
    }
    #pragma unroll
    for (int mt = 0; mt < 4; mt++)
      #pragma unroll
      for (int nt = 0; nt < 4; nt++)
        acc[mt][nt] = __builtin_amdgcn_mfma_f32_16x16x32_bf16(af[mt], bfr[nt], acc[mt][nt], 0, 0, 0);
    __syncthreads();
  }

  float* Cf = (float*)Cp;
  u16* Cb = (u16*)Cp;
  #pragma unroll
  for (int mt = 0; mt < 4; mt++) {
    #pragma unroll
    for (int nt = 0; nt < 4; nt++) {
      int col = bn + wn + nt * 16 + l16;
      if (col < N) {
        int row0 = bm + wm + mt * 16 + q * 4;
        #pragma unroll
        for (int r = 0; r < 4; r++) {
          size_t idx = (size_t)(row0 + r) * N + col;
          float v = acc[mt][nt][r];
          if (OUT_BF16) Cb[idx] = f2b(v); else Cf[idx] = v;
        }
      }
    }
  }
}

// ---------------- rmsnorm rows: fp32 [4096][stride] (first C cols) -> bf16 [4096][C] ----------------
__global__ __launch_bounds__(256)
void rmsnorm_rows(const float* __restrict__ in, u16* __restrict__ out, int C, int stride) {
  int row = blockIdx.x;
  const float* x = in + (size_t)row * stride;
  float ss = 0.f;
  for (int i = threadIdx.x; i < C; i += 256) { float v = x[i]; ss += v * v; }
  ss = waveReduceSum(ss);
  __shared__ float red[4];
  __shared__ float s_scale;
  int lane = threadIdx.x & 63, wid = threadIdx.x >> 6;
  if (lane == 0) red[wid] = ss;
  __syncthreads();
  if (threadIdx.x == 0)
    s_scale = rsqrtf((red[0] + red[1] + red[2] + red[3]) / (float)C + 1e-5f);
  __syncthreads();
  float sc = s_scale;
  u16* o = out + (size_t)row * C;
  for (int i = threadIdx.x; i < C; i += 256) o[i] = f2b(x[i] * sc);
}

// ---------------- rope + pack Q, PRESCALED by 1/sqrt(192) ----------------
// q2 bf16 [B*S][H*192] -> Q bf16 [B*H][S][192], row = scale*[roped q_rope(64) | q_nope(128)]
__global__ __launch_bounds__(256)
void rope_pack_q(const u16* __restrict__ q2, const float* __restrict__ fc, const float* __restrict__ fs,
                 u16* __restrict__ Q) {
  const float scale = 0.07216878364870323f;  // 1/sqrt(192)
  int bs = blockIdx.x;
  int b = bs >> 11, s = bs & 2047;
  __shared__ float c[32], sn[32];
  if (threadIdx.x < 32) {
    c[threadIdx.x] = fc[s * 32 + threadIdx.x];
    sn[threadIdx.x] = fs[s * 32 + threadIdx.x];
  }
  __syncthreads();
  const u16* qrow = q2 + (size_t)bs * 3072;
  for (int t = threadIdx.x; t < 512; t += 256) {
    int h = t >> 5, i = t & 31;
    float x0 = b2f(qrow[h * 192 + 128 + 2 * i]);
    float x1 = b2f(qrow[h * 192 + 128 + 2 * i + 1]);
    size_t base = ((size_t)(b * 16 + h) * 2048 + s) * 192;
    Q[base + 2 * i]     = f2b((x0 * c[i] - x1 * sn[i]) * scale);
    Q[base + 2 * i + 1] = f2b((x0 * sn[i] + x1 * c[i]) * scale);
  }
  for (int t = threadIdx.x; t < 2048; t += 256) {
    int h = t >> 7, j = t & 127;
    Q[((size_t)(b * 16 + h) * 2048 + s) * 192 + 64 + j] = f2b(b2f(qrow[h * 192 + j]) * scale);
  }
}

// ---------------- kv split: t13 fp32 [B*S][2112] cols 1536.. -> rmsnorm(kvl) + roped k_rope ----------------
__global__ __launch_bounds__(256)
void kv_split(const float* __restrict__ t13, const float* __restrict__ fc, const float* __restrict__ fs,
              u16* __restrict__ kvl, u16* __restrict__ krope) {
  int row = blockIdx.x;
  int s = row & 2047;
  const float* x = t13 + (size_t)row * 2112 + 1536;
  float ss = 0.f;
  for (int i = threadIdx.x; i < 512; i += 256) { float v = x[i]; ss += v * v; }
  ss = waveReduceSum(ss);
  __shared__ float red[4];
  __shared__ float s_scale;
  int lane = threadIdx.x & 63, wid = threadIdx.x >> 6;
  if (lane == 0) red[wid] = ss;
  __syncthreads();
  if (threadIdx.x == 0)
    s_scale = rsqrtf((red[0] + red[1] + red[2] + red[3]) * (1.0f / 512.0f) + 1e-5f);
  __syncthreads();
  float sc = s_scale;
  for (int i = threadIdx.x; i < 512; i += 256) kvl[(size_t)row * 512 + i] = f2b(x[i] * sc);
  if (threadIdx.x < 32) {
    int i = threadIdx.x;
    float cc = fc[s * 32 + i], sn = fs[s * 32 + i];
    float x0 = x[512 + 2 * i], x1 = x[512 + 2 * i + 1];
    krope[(size_t)row * 64 + 2 * i]     = f2b(x0 * cc - x1 * sn);
    krope[(size_t)row * 64 + 2 * i + 1] = f2b(x0 * sn + x1 * cc);
  }
}

// ---------------- assemble K chunked + V transposed chunked ----------------
// Kc[bh][kq 0..23][s 2048][8]  (dims kq*8..+7 of [rope64|nope128])
// Vt[bh][ks 0..255][dv 128][8] (keys ks*8..+7)
__global__ __launch_bounds__(256)
void assemble_kv2(const u16* __restrict__ kvb, const u16* __restrict__ krope,
                  u16* __restrict__ Kc, u16* __restrict__ Vt) {
  int ks = blockIdx.x;   // 0..255
  int bh = blockIdx.y;   // 0..31
  int b = bh >> 4, h = bh & 15;
  int t = threadIdx.x;
  if (t < 192) {
    int kq = t >> 3, sl = t & 7;
    int s = ks * 8 + sl;
    size_t bs = (size_t)(b * 2048 + s);
    uint4 v;
    if (kq < 8) v = *reinterpret_cast<const uint4*>(krope + bs * 64 + kq * 8);
    else        v = *reinterpret_cast<const uint4*>(kvb + bs * 4096 + h * 128 + (kq - 8) * 8);
    *reinterpret_cast<uint4*>(Kc + (((size_t)bh * 24 + kq) * 2048 + s) * 8) = v;
  }
  if (t < 128) {
    int dv = t;
    u16 tmp[8];
    #pragma unroll
    for (int j = 0; j < 8; j++) {
      int s = ks * 8 + j;
      tmp[j] = kvb[(size_t)(b * 2048 + s) * 4096 + 2048 + h * 128 + dv];
    }
    *reinterpret_cast<uint4*>(Vt + (((size_t)bh * 256 + ks) * 128 + dv) * 8) = *reinterpret_cast<uint4*>(tmp);
  }
}

// ---------------- MFMA flash attention v6 ----------------
// 128-query tiles, 4 waves x 32 queries (2x16 row sub-tiles): K/V LDS fragments are
// register-reused across the two row sub-tiles -> LDS read traffic per work halved.
// Double-buffered K/V staging, counted vmcnt(10): loads for step k+1 stay in flight
// across the barriers while step k computes (never drain to 0 mid-loop).
// Balanced pairs {t, 15-t}: every block does 17*128 = 2176 keys total. Grid 256.
// Q pre-scaled -> no-max softmax exact; l via constant ones-B-fragment MFMA.
__global__ __launch_bounds__(256, 1)
void flash_attn6(const u16* __restrict__ Q, const u16* __restrict__ Kc,
                 const u16* __restrict__ Vt, u16* __restrict__ O) {
  __shared__ __attribute__((aligned(16))) u16 Ks[2][24 * 64 * 8];  // 2x24.5 KB [kq][key][8]
  __shared__ __attribute__((aligned(16))) u16 Vs[2][8 * 128 * 8];  // 2x16 KB  [kc][dv][8]
  __shared__ __attribute__((aligned(16))) u16 Ps[4 * 32 * 72];     // 18 KB per-wave P, stride 72

  const int blk = blockIdx.x;          // 256 blocks
  const int xcd = blk & 7;
  const int i = blk >> 3;              // 0..31
  const int tpair = i & 7;             // 0..7
  const int bh = (xcd << 2) | (i >> 3);
  const int b = bh >> 4, h = bh & 15;
  const int tid = threadIdx.x, lane = tid & 63, wave = tid >> 6;
  const int quad = lane >> 4, l16 = lane & 15;
  u16* PsW = Ps + wave * 32 * 72;

  // constant ones-column B-fragment: B[n][k] = (n==0) ? 1 : 0
  bf16x8 onesf;
  #pragma unroll
  for (int j = 0; j < 8; j++) onesf[j] = (l16 == 0) ? (__bf16)1.0f : (__bf16)0.0f;

  auto stage = [&](u16* KsB, u16* VsB, int kk) {
    #pragma unroll
    for (int ii = 0; ii < 6; ii++) {
      int kq = wave * 6 + ii;
      gld16(Kc + (((size_t)bh * 24 + kq) * 2048 + kk + lane) * 8, KsB + kq * 64 * 8);
    }
    #pragma unroll
    for (int jj = 0; jj < 4; jj++) {
      int vc = wave * 4 + jj, kc = vc >> 1, dvh = vc & 1;
      gld16(Vt + (((size_t)bh * 256 + (kk >> 3) + kc) * 128 + dvh * 64 + lane) * 8,
            VsB + (kc * 128 + dvh * 64) * 8);
    }
  };

  for (int phase = 0; phase < 2; phase++) {
    const int qt = phase == 0 ? tpair : 15 - tpair;
    const int q0 = qt * 128;
    const int nk = (qt + 1) * 128;

    bf16x8 qf[2][6];
    #pragma unroll
    for (int mt = 0; mt < 2; mt++) {
      int qrow = q0 + wave * 32 + mt * 16 + l16;
      const u16* qp = Q + ((size_t)bh * 2048 + qrow) * 192 + quad * 8;
      #pragma unroll
      for (int kc = 0; kc < 6; kc++)
        qf[mt][kc] = *reinterpret_cast<const bf16x8*>(qp + kc * 32);
    }

    f32x4 zero = {0.f, 0.f, 0.f, 0.f};
    f32x4 oacc[2][9];
    #pragma unroll
    for (int mt = 0; mt < 2; mt++)
      #pragma unroll
      for (int nt = 0; nt < 9; nt++) oacc[mt][nt] = zero;

    for (int k0 = 0; k0 < nk; k0 += 64) {
      const int cur = (k0 >> 6) & 1;
      // BAR_a: all waves done computing previous step (safe to overwrite cur^1)
      __builtin_amdgcn_s_barrier();
      if (k0 == 0) stage(Ks[0], Vs[0], 0);               // prologue (after BAR_a)
      if (k0 + 64 < nk) {
        stage(Ks[cur ^ 1], Vs[cur ^ 1], k0 + 64);        // prefetch next step
        asm volatile("s_waitcnt vmcnt(10)" ::: "memory"); // cur loads done; next in flight
      } else {
        asm volatile("s_waitcnt vmcnt(0)" ::: "memory");
      }
      __builtin_amdgcn_sched_barrier(0);
      // BAR_b: every wave waited for its own cur loads -> all cur data visible
      __builtin_amdgcn_s_barrier();

      const u16* KsC = Ks[cur];
      const u16* VsC = Vs[cur];

      // QK^T (Q pre-scaled): K-fragments reused across both row sub-tiles
      f32x4 sacc[2][4];
      #pragma unroll
      for (int mt = 0; mt < 2; mt++)
        #pragma unroll
        for (int nt = 0; nt < 4; nt++) sacc[mt][nt] = zero;
      #pragma unroll
      for (int kc = 0; kc < 6; kc++) {
        #pragma unroll
        for (int nt = 0; nt < 4; nt++) {
          bf16x8 kb = *reinterpret_cast<const bf16x8*>(KsC + ((kc * 4 + quad) * 64 + nt * 16 + l16) * 8);
          sacc[0][nt] = __builtin_amdgcn_mfma_f32_16x16x32_bf16(qf[0][kc], kb, sacc[0][nt], 0, 0, 0);
          sacc[1][nt] = __builtin_amdgcn_mfma_f32_16x16x32_bf16(qf[1][kc], kb, sacc[1][nt], 0, 0, 0);
        }
      }

      // no-max softmax: P = exp(s) masked; no shuffles, no rescale
      #pragma unroll
      for (int mt = 0; mt < 2; mt++) {
        #pragma unroll
        for (int r = 0; r < 4; r++) {
          int qrow_g = q0 + wave * 32 + mt * 16 + quad * 4 + r;
          #pragma unroll
          for (int nt = 0; nt < 4; nt++) {
            int key = k0 + nt * 16 + l16;
            float p = (key <= qrow_g) ? __expf(sacc[mt][nt][r]) : 0.f;
            PsW[(mt * 16 + quad * 4 + r) * 72 + nt * 16 + l16] = f2b(p);
          }
        }
      }

      // PV (+ l via ones-fragment): V-fragments reused across both row sub-tiles
      #pragma unroll
      for (int kcp = 0; kcp < 2; kcp++) {
        bf16x8 pa0 = *reinterpret_cast<const bf16x8*>(PsW + (l16) * 72 + kcp * 32 + quad * 8);
        bf16x8 pa1 = *reinterpret_cast<const bf16x8*>(PsW + (16 + l16) * 72 + kcp * 32 + quad * 8);
        #pragma unroll
        for (int nt = 0; nt < 8; nt++) {
          bf16x8 vb = *reinterpret_cast<const bf16x8*>(VsC + ((kcp * 4 + quad) * 128 + nt * 16 + l16) * 8);
          oacc[0][nt] = __builtin_amdgcn_mfma_f32_16x16x32_bf16(pa0, vb, oacc[0][nt], 0, 0, 0);
          oacc[1][nt] = __builtin_amdgcn_mfma_f32_16x16x32_bf16(pa1, vb, oacc[1][nt], 0, 0, 0);
        }
        oacc[0][8] = __builtin_amdgcn_mfma_f32_16x16x32_bf16(pa0, onesf, oacc[0][8], 0, 0, 0);
        oacc[1][8] = __builtin_amdgcn_mfma_f32_16x16x32_bf16(pa1, onesf, oacc[1][8], 0, 0, 0);
      }
    }

    // epilogue: l sits in oacc[mt][8][r] at l16==0 of each quad; broadcast within quad
    #pragma unroll
    for (int mt = 0; mt < 2; mt++) {
      #pragma unroll
      for (int r = 0; r < 4; r++) {
        float l = __shfl(oacc[mt][8][r], lane & 48, 64);
        float inv = 1.0f / l;
        int s = q0 + wave * 32 + mt * 16 + quad * 4 + r;
        #pragma unroll
        for (int nt = 0; nt < 8; nt++)
          O[((size_t)b * 2048 + s) * 2048 + h * 128 + nt * 16 + l16] = f2b(oacc[mt][nt][r] * inv);
      }
    }
  }
}

// ---------------- launch ----------------
extern "C" void kernel_launch(void* const* d_in, const int* in_sizes, int n_in,
                              void* d_out, int out_size, void* d_ws, size_t ws_size,
                              hipStream_t stream) {
  (void)in_sizes; (void)n_in; (void)out_size; (void)ws_size;
  const float* hs   = (const float*)d_in[0];
  const float* fc   = (const float*)d_in[2];
  const float* fs   = (const float*)d_in[3];
  const float* Wqd  = (const float*)d_in[4];
  const float* Wkvd = (const float*)d_in[5];
  const float* Wqu  = (const float*)d_in[6];
  const float* Wkvu = (const float*)d_in[7];
  const float* Wo   = (const float*)d_in[8];

  char* ws = (char*)d_ws;
  size_t off = 0;
  auto alloc = [&](size_t bytes) { size_t o = off; off += (bytes + 255) & ~(size_t)255; return o; };
  const size_t oHS   = alloc(16777216);  // hs_bf bf16 [4096][2048]
  const size_t oRA   = alloc(16777216);  // Vt bf16 [32][256][128][8]
  const size_t oRB   = alloc(25165824);  // q2 bf16 [4096][3072] -> Kc bf16
  const size_t oRC   = alloc(12582912);  // qlat bf16 [4096][1536]
  const size_t oRD   = alloc(25165824);  // Q bf16 [B*H][S][192]
  const size_t oRE   = alloc(34603008);  // t13 f32 [4096][2112] -> kvb bf16 [4096][4096] -> attn_out
  const size_t oKVL  = alloc(4194304);   // kvl bf16 [4096][512]
  const size_t oKR   = alloc(524288);    // krope bf16 [4096][64]
  const size_t oW13T  = alloc(8650752);  // [2112][2048] bf16 (WqdT rows 0..1535, WkvdT rows 1536..)
  const size_t oWquT  = alloc(9437184);
  const size_t oWkvuT = alloc(4194304);
  const size_t oWoT   = alloc(8388608);

  u16* hs_bf = (u16*)(ws + oHS);
  u16* Vt   = (u16*)(ws + oRA);
  u16* q2   = (u16*)(ws + oRB);
  u16* Kc   = (u16*)(ws + oRB);
  u16* qlat = (u16*)(ws + oRC);
  u16* Qb   = (u16*)(ws + oRD);
  float* t13 = (float*)(ws + oRE);
  u16* kvb  = (u16*)(ws + oRE);
  u16* attn_out = (u16*)(ws + oRE);
  u16* kvl  = (u16*)(ws + oKVL);
  u16* krope = (u16*)(ws + oKR);
  u16* W13T  = (u16*)(ws + oW13T);
  u16* WquT  = (u16*)(ws + oWquT);
  u16* WkvuT = (u16*)(ws + oWkvuT);
  u16* WoT   = (u16*)(ws + oWoT);

  cvt_f32_bf16<<<8192, 256, 0, stream>>>(hs, hs_bf, 2097152);
  dim3 tb(32, 8);
  transpose_f32_bf16<<<dim3(48, 64), tb, 0, stream>>>(Wqd, W13T, 2048, 1536);
  transpose_f32_bf16<<<dim3(18, 64), tb, 0, stream>>>(Wkvd, W13T + (size_t)1536 * 2048, 2048, 576);
  transpose_f32_bf16<<<dim3(96, 48), tb, 0, stream>>>(Wqu, WquT, 1536, 3072);
  transpose_f32_bf16<<<dim3(128, 16), tb, 0, stream>>>(Wkvu, WkvuT, 512, 4096);
  transpose_f32_bf16<<<dim3(64, 64), tb, 0, stream>>>(Wo, WoT, 2048, 2048);

  // fused down-projections: t13 = hs @ [Wq_down | Wkv_down]
  gemm_bt<0><<<dim3(17, 32), 256, 0, stream>>>(hs_bf, W13T, t13, 4096, 2112, 2048);
  // q path
  rmsnorm_rows<<<4096, 256, 0, stream>>>(t13, qlat, 1536, 2112);
  gemm_bt<1><<<dim3(24, 32), 256, 0, stream>>>(qlat, WquT, q2, 4096, 3072, 1536);
  rope_pack_q<<<4096, 256, 0, stream>>>(q2, fc, fs, Qb);
  // kv path
  kv_split<<<4096, 256, 0, stream>>>(t13, fc, fs, kvl, krope);
  gemm_bt<1><<<dim3(32, 32), 256, 0, stream>>>(kvl, WkvuT, kvb, 4096, 4096, 512);
  assemble_kv2<<<dim3(256, 32), 256, 0, stream>>>(kvb, krope, Kc, Vt);
  // attention (128-row tiles, dbuf + counted vmcnt, balanced pairs, XCD-local)
  flash_attn6<<<dim3(256), 256, 0, stream>>>(Qb, Kc, Vt, attn_out);
  // output projection (fp32 out)
  gemm_bt<0><<<dim3(16, 32), 256, 0, stream>>>(attn_out, WoT, (float*)d_out, 4096, 2048, 2048);
}

// Round 8
// 470.740 us; speedup vs baseline: 1.0650x; 1.0650x over previous
//
#include <hip/hip_runtime.h>
#include <math.h>

// DeepSeekV3 MLA forward, MI355X gfx950.
// I/O fp32; internal math bf16 MFMA.
// Flash v7: v5's measured-good 64-row/wave, 2-blocks/CU TLP structure
//           + K-only double-buffer with counted vmcnt split waits (T4):
//           K prefetched a full step ahead (vmcnt(10) at BAR_b), V staged in-step
//           and waited only before PV (vmcnt(6) at BAR_c) -> no vmcnt(0) drain mid-loop.
//           LDS 74 KB -> still 2 blocks/CU. VGPR capped 128 via launch_bounds(256,2).
// GEMMs r7 (measured win): global_load_lds(16B) staging, XOR-swizzled unit map,
//           XCD-chunked block swizzle. 128x128, BK=32.
// B=2 S=2048 D=2048 H=16 NOPE=128 ROPE=64 DV=128 DQK=192 QLR=1536 KVLR=512

typedef unsigned short u16;
typedef __attribute__((ext_vector_type(8))) __bf16 bf16x8;
typedef __attribute__((ext_vector_type(4))) float f32x4;

#define DEV static __device__ __forceinline__

DEV float b2f(u16 v) { return __uint_as_float(((unsigned int)v) << 16); }
DEV u16 f2b(float f) {
  unsigned int u = __float_as_uint(f);
  u += 0x7fffu + ((u >> 16) & 1u);   // round-to-nearest-even
  return (u16)(u >> 16);
}

DEV float waveReduceSum(float v) {
  #pragma unroll
  for (int o = 32; o > 0; o >>= 1) v += __shfl_down(v, o, 64);
  return v;
}

// async global->LDS, 16B per lane; LDS dest = wave-uniform base + lane*16
DEV void gld16(const u16* g, u16* l) {
  __builtin_amdgcn_global_load_lds((const __attribute__((address_space(1))) void*)g,
                                   (__attribute__((address_space(3))) void*)l, 16, 0, 0);
}

// ---------------- convert fp32 -> bf16 (flat) ----------------
__global__ __launch_bounds__(256)
void cvt_f32_bf16(const float* __restrict__ in, u16* __restrict__ out, int n4) {
  int i = blockIdx.x * 256 + threadIdx.x;
  if (i < n4) {
    float4 v = reinterpret_cast<const float4*>(in)[i];
    ushort4 o;
    o.x = f2b(v.x); o.y = f2b(v.y); o.z = f2b(v.z); o.w = f2b(v.w);
    reinterpret_cast<ushort4*>(out)[i] = o;
  }
}

// ---------------- transpose+convert: in f32 [R][C] -> out bf16 [C][R] ----------------
__global__ __launch_bounds__(256)
void transpose_f32_bf16(const float* __restrict__ in, u16* __restrict__ out, int R, int C) {
  __shared__ u16 tile[32][33];
  int c0 = blockIdx.x * 32, r0 = blockIdx.y * 32;
  for (int i = threadIdx.y; i < 32; i += 8)
    tile[i][threadIdx.x] = f2b(in[(size_t)(r0 + i) * C + c0 + threadIdx.x]);
  __syncthreads();
  for (int i = threadIdx.y; i < 32; i += 8)
    out[(size_t)(c0 + i) * R + r0 + threadIdx.x] = tile[threadIdx.x][i];
}

// ---------------- MFMA bt-GEMM: C[M][N] = A[M][K] * BT[N][K]^T ----------------
// 128x128 tile, 4 waves, BK=32.
// LDS unit map (16B units): u = row*4 + (kq ^ ((row>>1)&3)), row 0..127, kq 0..3.
// Staging: global_load_lds 16B/lane, dest = wave-uniform chunk base (linear),
//   per-lane source decoded from u = jb + lane: row = u>>2, kq = (u&3)^((u>>3)&3).
//   -> 4 consecutive lanes read the same row's 4 K-octets (64B segment, permuted).
// Fragment read: unit (row<<2)|(q^((row>>1)&3)) -> 2-way bank aliasing (free).
// XCD swizzle: contiguous row-major tile chunk per XCD.
template<int OUT_BF16>
__global__ __launch_bounds__(256)
void gemm_bt(const u16* __restrict__ A, const u16* __restrict__ BT, void* __restrict__ Cp,
             int M, int N, int K) {
  __shared__ __attribute__((aligned(16))) u16 As[4096];
  __shared__ __attribute__((aligned(16))) u16 Bs[4096];
  const int tid = threadIdx.x;
  const int lane = tid & 63;
  const int wave = tid >> 6;
  const int wm = (wave >> 1) * 64;
  const int wn = (wave & 1) * 64;
  const int q = lane >> 4;
  const int l16 = lane & 15;

  // XCD-chunked bijective swizzle: XCD k = (orig%8) gets work tiles [k*cpx, (k+1)*cpx)
  const int gx = gridDim.x;
  const int nwg = gx * gridDim.y;
  const int orig = blockIdx.y * gx + blockIdx.x;
  const int cpx = nwg >> 3;
  const int swz = (orig & 7) * cpx + (orig >> 3);
  const int bm = (swz / gx) * 128;
  const int bn = (swz % gx) * 128;

  f32x4 zero = {0.f, 0.f, 0.f, 0.f};
  f32x4 acc[4][4];
  #pragma unroll
  for (int i = 0; i < 4; i++)
    #pragma unroll
    for (int j = 0; j < 4; j++) acc[i][j] = zero;

  for (int k0 = 0; k0 < K; k0 += 32) {
    #pragma unroll
    for (int i = 0; i < 2; i++) {
      int jb = i * 256 + wave * 64;      // chunk base, 16B units (wave-uniform)
      int u = jb + lane;
      int row = u >> 2;
      int kq = (u & 3) ^ ((u >> 3) & 3);
      gld16(A + (size_t)(bm + row) * K + k0 + kq * 8, As + jb * 8);
      int rB = bn + row;
      if (rB >= N) rB = N - 1;           // clamp: finite garbage, cols >= N never stored
      gld16(BT + (size_t)rB * K + k0 + kq * 8, Bs + jb * 8);
    }
    __syncthreads();   // vmcnt(0) drained before barrier: staging visible
    bf16x8 af[4], bfr[4];
    #pragma unroll
    for (int t = 0; t < 4; t++) {
      int rowA = wm + t * 16 + l16;
      int rowB = wn + t * 16 + l16;
      int uA = (rowA << 2) | (q ^ ((rowA >> 1) & 3));
      int uB = (rowB << 2) | (q ^ ((rowB >> 1) & 3));
      af[t]  = *reinterpret_cast<const bf16x8*>(As + uA * 8);
      bfr[t] = *reinterpret_cast<const bf16x8*>(Bs + uB * 8);
    }
    #pragma unroll
    for (int mt = 0; mt < 4; mt++)
      #pragma unroll
      for (int nt = 0; nt < 4; nt++)
        acc[mt][nt] = __builtin_amdgcn_mfma_f32_16x16x32_bf16(af[mt], bfr[nt], acc[mt][nt], 0, 0, 0);
    __syncthreads();
  }

  float* Cf = (float*)Cp;
  u16* Cb = (u16*)Cp;
  #pragma unroll
  for (int mt = 0; mt < 4; mt++) {
    #pragma unroll
    for (int nt = 0; nt < 4; nt++) {
      int col = bn + wn + nt * 16 + l16;
      if (col < N) {
        int row0 = bm + wm + mt * 16 + q * 4;
        #pragma unroll
        for (int r = 0; r < 4; r++) {
          size_t idx = (size_t)(row0 + r) * N + col;
          float v = acc[mt][nt][r];
          if (OUT_BF16) Cb[idx] = f2b(v); else Cf[idx] = v;
        }
      }
    }
  }
}

// ---------------- rmsnorm rows: fp32 [4096][stride] (first C cols) -> bf16 [4096][C] ----------------
__global__ __launch_bounds__(256)
void rmsnorm_rows(const float* __restrict__ in, u16* __restrict__ out, int C, int stride) {
  int row = blockIdx.x;
  const float* x = in + (size_t)row * stride;
  float ss = 0.f;
  for (int i = threadIdx.x; i < C; i += 256) { float v = x[i]; ss += v * v; }
  ss = waveReduceSum(ss);
  __shared__ float red[4];
  __shared__ float s_scale;
  int lane = threadIdx.x & 63, wid = threadIdx.x >> 6;
  if (lane == 0) red[wid] = ss;
  __syncthreads();
  if (threadIdx.x == 0)
    s_scale = rsqrtf((red[0] + red[1] + red[2] + red[3]) / (float)C + 1e-5f);
  __syncthreads();
  float sc = s_scale;
  u16* o = out + (size_t)row * C;
  for (int i = threadIdx.x; i < C; i += 256) o[i] = f2b(x[i] * sc);
}

// ---------------- rope + pack Q, PRESCALED by 1/sqrt(192) ----------------
// q2 bf16 [B*S][H*192] -> Q bf16 [B*H][S][192], row = scale*[roped q_rope(64) | q_nope(128)]
__global__ __launch_bounds__(256)
void rope_pack_q(const u16* __restrict__ q2, const float* __restrict__ fc, const float* __restrict__ fs,
                 u16* __restrict__ Q) {
  const float scale = 0.07216878364870323f;  // 1/sqrt(192)
  int bs = blockIdx.x;
  int b = bs >> 11, s = bs & 2047;
  __shared__ float c[32], sn[32];
  if (threadIdx.x < 32) {
    c[threadIdx.x] = fc[s * 32 + threadIdx.x];
    sn[threadIdx.x] = fs[s * 32 + threadIdx.x];
  }
  __syncthreads();
  const u16* qrow = q2 + (size_t)bs * 3072;
  for (int t = threadIdx.x; t < 512; t += 256) {
    int h = t >> 5, i = t & 31;
    float x0 = b2f(qrow[h * 192 + 128 + 2 * i]);
    float x1 = b2f(qrow[h * 192 + 128 + 2 * i + 1]);
    size_t base = ((size_t)(b * 16 + h) * 2048 + s) * 192;
    Q[base + 2 * i]     = f2b((x0 * c[i] - x1 * sn[i]) * scale);
    Q[base + 2 * i + 1] = f2b((x0 * sn[i] + x1 * c[i]) * scale);
  }
  for (int t = threadIdx.x; t < 2048; t += 256) {
    int h = t >> 7, j = t & 127;
    Q[((size_t)(b * 16 + h) * 2048 + s) * 192 + 64 + j] = f2b(b2f(qrow[h * 192 + j]) * scale);
  }
}

// ---------------- kv split: t13 fp32 [B*S][2112] cols 1536.. -> rmsnorm(kvl) + roped k_rope ----------------
__global__ __launch_bounds__(256)
void kv_split(const float* __restrict__ t13, const float* __restrict__ fc, const float* __restrict__ fs,
              u16* __restrict__ kvl, u16* __restrict__ krope) {
  int row = blockIdx.x;
  int s = row & 2047;
  const float* x = t13 + (size_t)row * 2112 + 1536;
  float ss = 0.f;
  for (int i = threadIdx.x; i < 512; i += 256) { float v = x[i]; ss += v * v; }
  ss = waveReduceSum(ss);
  __shared__ float red[4];
  __shared__ float s_scale;
  int lane = threadIdx.x & 63, wid = threadIdx.x >> 6;
  if (lane == 0) red[wid] = ss;
  __syncthreads();
  if (threadIdx.x == 0)
    s_scale = rsqrtf((red[0] + red[1] + red[2] + red[3]) * (1.0f / 512.0f) + 1e-5f);
  __syncthreads();
  float sc = s_scale;
  for (int i = threadIdx.x; i < 512; i += 256) kvl[(size_t)row * 512 + i] = f2b(x[i] * sc);
  if (threadIdx.x < 32) {
    int i = threadIdx.x;
    float cc = fc[s * 32 + i], sn = fs[s * 32 + i];
    float x0 = x[512 + 2 * i], x1 = x[512 + 2 * i + 1];
    krope[(size_t)row * 64 + 2 * i]     = f2b(x0 * cc - x1 * sn);
    krope[(size_t)row * 64 + 2 * i + 1] = f2b(x0 * sn + x1 * cc);
  }
}

// ---------------- assemble K chunked + V transposed chunked ----------------
// Kc[bh][kq 0..23][s 2048][8]  (dims kq*8..+7 of [rope64|nope128])
// Vt[bh][ks 0..255][dv 128][8] (keys ks*8..+7)
__global__ __launch_bounds__(256)
void assemble_kv2(const u16* __restrict__ kvb, const u16* __restrict__ krope,
                  u16* __restrict__ Kc, u16* __restrict__ Vt) {
  int ks = blockIdx.x;   // 0..255
  int bh = blockIdx.y;   // 0..31
  int b = bh >> 4, h = bh & 15;
  int t = threadIdx.x;
  if (t < 192) {
    int kq = t >> 3, sl = t & 7;
    int s = ks * 8 + sl;
    size_t bs = (size_t)(b * 2048 + s);
    uint4 v;
    if (kq < 8) v = *reinterpret_cast<const uint4*>(krope + bs * 64 + kq * 8);
    else        v = *reinterpret_cast<const uint4*>(kvb + bs * 4096 + h * 128 + (kq - 8) * 8);
    *reinterpret_cast<uint4*>(Kc + (((size_t)bh * 24 + kq) * 2048 + s) * 8) = v;
  }
  if (t < 128) {
    int dv = t;
    u16 tmp[8];
    #pragma unroll
    for (int j = 0; j < 8; j++) {
      int s = ks * 8 + j;
      tmp[j] = kvb[(size_t)(b * 2048 + s) * 4096 + 2048 + h * 128 + dv];
    }
    *reinterpret_cast<uint4*>(Vt + (((size_t)bh * 256 + ks) * 128 + dv) * 8) = *reinterpret_cast<uint4*>(tmp);
  }
}

// ---------------- MFMA flash attention v7 ----------------
// v5 structure (64 q/wave tile, 512 blocks, balanced pairs {t,31-t}, XCD-local bh,
// no-max softmax, l via ones-fragment) + K-only double-buffer with counted vmcnt:
//   BAR_a -> issue V(cur)x4 + K(next)x6 -> vmcnt(10) [K(cur) done, V+Knext in flight]
//   -> BAR_b -> QK^T + softmax -> vmcnt(6) [V done, Knext in flight] -> BAR_c -> PV.
// No vmcnt(0) drain mid-loop; K latency hidden under previous step, V under QK^T.
// LDS 74 KB, VGPR <=128 -> 2 blocks/CU (TLP overlap preserved, the v6 lesson).
__global__ __launch_bounds__(256, 2)
void flash_attn7(const u16* __restrict__ Q, const u16* __restrict__ Kc,
                 const u16* __restrict__ Vt, u16* __restrict__ O) {
  __shared__ __attribute__((aligned(16))) u16 Ks[2][24 * 64 * 8];  // 49 KB dbuf [kq][key][8]
  __shared__ __attribute__((aligned(16))) u16 Vs[8 * 128 * 8];     // 16 KB [kc][dv][8]
  __shared__ __attribute__((aligned(16))) u16 Ps[4 * 16 * 72];     // 9 KB per-wave P, stride 72

  const int blk = blockIdx.x;
  const int bh = ((blk & 7) << 2) | (blk >> 7);
  const int tpair = (blk >> 3) & 15;
  const int b = bh >> 4, h = bh & 15;
  const int tid = threadIdx.x, lane = tid & 63, wave = tid >> 6;
  const int quad = lane >> 4, l16 = lane & 15;
  u16* PsW = Ps + wave * 16 * 72;

  // constant ones-column B-fragment: B[n][k] = (n==0) ? 1 : 0
  bf16x8 onesf;
  #pragma unroll
  for (int j = 0; j < 8; j++) onesf[j] = (l16 == 0) ? (__bf16)1.0f : (__bf16)0.0f;

  auto stageK = [&](u16* KsB, int kk) {
    #pragma unroll
    for (int ii = 0; ii < 6; ii++) {
      int kq = wave * 6 + ii;
      gld16(Kc + (((size_t)bh * 24 + kq) * 2048 + kk + lane) * 8, KsB + kq * 64 * 8);
    }
  };
  auto stageV = [&](int kk) {
    #pragma unroll
    for (int jj = 0; jj < 4; jj++) {
      int vc = wave * 4 + jj, kc = vc >> 1, dvh = vc & 1;
      gld16(Vt + (((size_t)bh * 256 + (kk >> 3) + kc) * 128 + dvh * 64 + lane) * 8,
            Vs + (kc * 128 + dvh * 64) * 8);
    }
  };

  for (int phase = 0; phase < 2; phase++) {
    const int qt = phase == 0 ? tpair : 31 - tpair;
    const int q0 = qt * 64;
    const int nk = (qt + 1) * 64;

    bf16x8 qf[6];
    {
      int qrow = q0 + wave * 16 + l16;
      const u16* qp = Q + ((size_t)bh * 2048 + qrow) * 192 + quad * 8;
      #pragma unroll
      for (int kc = 0; kc < 6; kc++)
        qf[kc] = *reinterpret_cast<const bf16x8*>(qp + kc * 32);
    }

    f32x4 zero = {0.f, 0.f, 0.f, 0.f};
    f32x4 oacc[9];
    #pragma unroll
    for (int nt = 0; nt < 9; nt++) oacc[nt] = zero;

    for (int k0 = 0; k0 < nk; k0 += 64) {
      const int cur = (k0 >> 6) & 1;
      const bool hasnext = (k0 + 64 < nk);

      // BAR_a: all waves finished prev PV (Vs free) and prev QK^T (Ks[cur^1] free)
      __builtin_amdgcn_s_barrier();
      __builtin_amdgcn_sched_barrier(0);
      if (k0 == 0) stageK(Ks[0], 0);     // first K (oldest in FIFO -> retired by vmcnt(10))
      stageV(k0);
      if (hasnext) {
        stageK(Ks[cur ^ 1], k0 + 64);    // prefetch next K; stays in flight past BAR_b
        asm volatile("s_waitcnt vmcnt(10)" ::: "memory");  // K(cur) done; V+Knext flying
      } else {
        asm volatile("s_waitcnt vmcnt(4)" ::: "memory");   // K(cur) done; V flying
      }
      __builtin_amdgcn_sched_barrier(0);
      __builtin_amdgcn_s_barrier();      // BAR_b: K(cur) visible to all waves
      __builtin_amdgcn_sched_barrier(0);

      const u16* KsC = Ks[cur];

      // QK^T (Q pre-scaled)
      f32x4 sacc[4];
      #pragma unroll
      for (int nt = 0; nt < 4; nt++) sacc[nt] = zero;
      #pragma unroll
      for (int kc = 0; kc < 6; kc++) {
        #pragma unroll
        for (int nt = 0; nt < 4; nt++) {
          bf16x8 kb = *reinterpret_cast<const bf16x8*>(KsC + ((kc * 4 + quad) * 64 + nt * 16 + l16) * 8);
          sacc[nt] = __builtin_amdgcn_mfma_f32_16x16x32_bf16(qf[kc], kb, sacc[nt], 0, 0, 0);
        }
      }

      // no-max softmax: P = exp(s) masked; no shuffles, no rescale
      #pragma unroll
      for (int r = 0; r < 4; r++) {
        int qrow_g = q0 + wave * 16 + quad * 4 + r;
        #pragma unroll
        for (int nt = 0; nt < 4; nt++) {
          int key = k0 + nt * 16 + l16;
          float p = (key <= qrow_g) ? __expf(sacc[nt][r]) : 0.f;
          PsW[(quad * 4 + r) * 72 + nt * 16 + l16] = f2b(p);
        }
      }

      if (hasnext) asm volatile("s_waitcnt vmcnt(6)" ::: "memory");  // V done; Knext flying
      else         asm volatile("s_waitcnt vmcnt(0)" ::: "memory");
      __builtin_amdgcn_sched_barrier(0);
      __builtin_amdgcn_s_barrier();      // BAR_c: V(cur) visible to all waves
      __builtin_amdgcn_sched_barrier(0);

      // PV (+ l via ones-fragment): P from wave-private LDS (A-layout)
      #pragma unroll
      for (int kcp = 0; kcp < 2; kcp++) {
        bf16x8 pa = *reinterpret_cast<const bf16x8*>(PsW + l16 * 72 + kcp * 32 + quad * 8);
        #pragma unroll
        for (int nt = 0; nt < 8; nt++) {
          bf16x8 vb = *reinterpret_cast<const bf16x8*>(Vs + ((kcp * 4 + quad) * 128 + nt * 16 + l16) * 8);
          oacc[nt] = __builtin_amdgcn_mfma_f32_16x16x32_bf16(pa, vb, oacc[nt], 0, 0, 0);
        }
        oacc[8] = __builtin_amdgcn_mfma_f32_16x16x32_bf16(pa, onesf, oacc[8], 0, 0, 0);
      }
    }

    // epilogue: l sits in oacc[8][r] at l16==0 of each quad; broadcast within quad
    #pragma unroll
    for (int r = 0; r < 4; r++) {
      float l = __shfl(oacc[8][r], lane & 48, 64);
      float inv = 1.0f / l;
      int s = q0 + wave * 16 + quad * 4 + r;
      #pragma unroll
      for (int nt = 0; nt < 8; nt++)
        O[((size_t)b * 2048 + s) * 2048 + h * 128 + nt * 16 + l16] = f2b(oacc[nt][r] * inv);
    }
  }
}

// ---------------- launch ----------------
extern "C" void kernel_launch(void* const* d_in, const int* in_sizes, int n_in,
                              void* d_out, int out_size, void* d_ws, size_t ws_size,
                              hipStream_t stream) {
  (void)in_sizes; (void)n_in; (void)out_size; (void)ws_size;
  const float* hs   = (const float*)d_in[0];
  const float* fc   = (const float*)d_in[2];
  const float* fs   = (const float*)d_in[3];
  const float* Wqd  = (const float*)d_in[4];
  const float* Wkvd = (const float*)d_in[5];
  const float* Wqu  = (const float*)d_in[6];
  const float* Wkvu = (const float*)d_in[7];
  const float* Wo   = (const float*)d_in[8];

  char* ws = (char*)d_ws;
  size_t off = 0;
  auto alloc = [&](size_t bytes) { size_t o = off; off += (bytes + 255) & ~(size_t)255; return o; };
  const size_t oHS   = alloc(16777216);  // hs_bf bf16 [4096][2048]
  const size_t oRA   = alloc(16777216);  // Vt bf16 [32][256][128][8]
  const size_t oRB   = alloc(25165824);  // q2 bf16 [4096][3072] -> Kc bf16
  const size_t oRC   = alloc(12582912);  // qlat bf16 [4096][1536]
  const size_t oRD   = alloc(25165824);  // Q bf16 [B*H][S][192]
  const size_t oRE   = alloc(34603008);  // t13 f32 [4096][2112] -> kvb bf16 [4096][4096] -> attn_out
  const size_t oKVL  = alloc(4194304);   // kvl bf16 [4096][512]
  const size_t oKR   = alloc(524288);    // krope bf16 [4096][64]
  const size_t oW13T  = alloc(8650752);  // [2112][2048] bf16 (WqdT rows 0..1535, WkvdT rows 1536..)
  const size_t oWquT  = alloc(9437184);
  const size_t oWkvuT = alloc(4194304);
  const size_t oWoT   = alloc(8388608);

  u16* hs_bf = (u16*)(ws + oHS);
  u16* Vt   = (u16*)(ws + oRA);
  u16* q2   = (u16*)(ws + oRB);
  u16* Kc   = (u16*)(ws + oRB);
  u16* qlat = (u16*)(ws + oRC);
  u16* Qb   = (u16*)(ws + oRD);
  float* t13 = (float*)(ws + oRE);
  u16* kvb  = (u16*)(ws + oRE);
  u16* attn_out = (u16*)(ws + oRE);
  u16* kvl  = (u16*)(ws + oKVL);
  u16* krope = (u16*)(ws + oKR);
  u16* W13T  = (u16*)(ws + oW13T);
  u16* WquT  = (u16*)(ws + oWquT);
  u16* WkvuT = (u16*)(ws + oWkvuT);
  u16* WoT   = (u16*)(ws + oWoT);

  cvt_f32_bf16<<<8192, 256, 0, stream>>>(hs, hs_bf, 2097152);
  dim3 tb(32, 8);
  transpose_f32_bf16<<<dim3(48, 64), tb, 0, stream>>>(Wqd, W13T, 2048, 1536);
  transpose_f32_bf16<<<dim3(18, 64), tb, 0, stream>>>(Wkvd, W13T + (size_t)1536 * 2048, 2048, 576);
  transpose_f32_bf16<<<dim3(96, 48), tb, 0, stream>>>(Wqu, WquT, 1536, 3072);
  transpose_f32_bf16<<<dim3(128, 16), tb, 0, stream>>>(Wkvu, WkvuT, 512, 4096);
  transpose_f32_bf16<<<dim3(64, 64), tb, 0, stream>>>(Wo, WoT, 2048, 2048);

  // fused down-projections: t13 = hs @ [Wq_down | Wkv_down]
  gemm_bt<0><<<dim3(17, 32), 256, 0, stream>>>(hs_bf, W13T, t13, 4096, 2112, 2048);
  // q path
  rmsnorm_rows<<<4096, 256, 0, stream>>>(t13, qlat, 1536, 2112);
  gemm_bt<1><<<dim3(24, 32), 256, 0, stream>>>(qlat, WquT, q2, 4096, 3072, 1536);
  rope_pack_q<<<4096, 256, 0, stream>>>(q2, fc, fs, Qb);
  // kv path
  kv_split<<<4096, 256, 0, stream>>>(t13, fc, fs, kvl, krope);
  gemm_bt<1><<<dim3(32, 32), 256, 0, stream>>>(kvl, WkvuT, kvb, 4096, 4096, 512);
  assemble_kv2<<<dim3(256, 32), 256, 0, stream>>>(kvb, krope, Kc, Vt);
  // attention (v5 TLP structure + K-dbuf counted vmcnt)
  flash_attn7<<<dim3(512), 256, 0, stream>>>(Qb, Kc, Vt, attn_out);
  // output projection (fp32 out)
  gemm_bt<0><<<dim3(16, 32), 256, 0, stream>>>(attn_out, WoT, (float*)d_out, 4096, 2048, 2048);
}

// Round 10
// 446.229 us; speedup vs baseline: 1.1235x; 1.0549x over previous
//
#include <hip/hip_runtime.h>
#include <math.h>

// DeepSeekV3 MLA forward, MI355X gfx950.
// I/O fp32; internal math bf16 MFMA.
// Flash v8b: v7 structure (measured 78.4) + exp2-domain softmax via
//            __builtin_amdgcn_exp2f (COMPILER-emitted v_exp_f32: MFMA-read and
//            TRANS hazards handled; round-9's raw inline asm bypassed the hazard
//            recognizer -> sporadic stale reads, absmax 0.36), native RTNE bf16
//            cast, wave-uniform causal-mask hoist.
// GEMMs r8: r7 body (gld_lds swizzled staging + XCD chunk swizzle, measured win)
//           + q-up/kv-up fused into ONE launch (1792 blocks ~ 7/CU concurrency).
// Glue r8: 5 transposes -> 1 kernel; rmsnorm+kv_split -> 1 kernel. 14 -> 9 launches.
// B=2 S=2048 D=2048 H=16 NOPE=128 ROPE=64 DV=128 DQK=192 QLR=1536 KVLR=512

typedef unsigned short u16;
typedef __attribute__((ext_vector_type(8))) __bf16 bf16x8;
typedef __attribute__((ext_vector_type(4))) float f32x4;

#define DEV static __device__ __forceinline__

#if __has_builtin(__builtin_amdgcn_exp2f)
#define EXP2(x) __builtin_amdgcn_exp2f(x)
#else
#define EXP2(x) exp2f(x)
#endif

DEV float b2f(u16 v) { return __uint_as_float(((unsigned int)v) << 16); }
DEV u16 f2b(float f) {
  unsigned int u = __float_as_uint(f);
  u += 0x7fffu + ((u >> 16) & 1u);   // round-to-nearest-even
  return (u16)(u >> 16);
}
// native RTNE cvt -- compiler-generated, 1 instr, hazard-safe
DEV u16 f2b_hw(float f) {
  __bf16 h = (__bf16)f;
  u16 r;
  __builtin_memcpy(&r, &h, 2);
  return r;
}

DEV float waveReduceSum(float v) {
  #pragma unroll
  for (int o = 32; o > 0; o >>= 1) v += __shfl_down(v, o, 64);
  return v;
}

// async global->LDS, 16B per lane; LDS dest = wave-uniform base + lane*16
DEV void gld16(const u16* g, u16* l) {
  __builtin_amdgcn_global_load_lds((const __attribute__((address_space(1))) void*)g,
                                   (__attribute__((address_space(3))) void*)l, 16, 0, 0);
}

// ---------------- convert fp32 -> bf16 (flat) ----------------
__global__ __launch_bounds__(256)
void cvt_f32_bf16(const float* __restrict__ in, u16* __restrict__ out, int n4) {
  int i = blockIdx.x * 256 + threadIdx.x;
  if (i < n4) {
    float4 v = reinterpret_cast<const float4*>(in)[i];
    ushort4 o;
    o.x = f2b(v.x); o.y = f2b(v.y); o.z = f2b(v.z); o.w = f2b(v.w);
    reinterpret_cast<ushort4*>(out)[i] = o;
  }
}

// ---------------- fused transpose+convert of all 5 weights ----------------
// jobs (in f32 [R][C] -> out bf16 [C][R]), 32x32 tiles, block (32,8):
//  j0 Wqd  -> W13T              R=2048 C=1536 gx=48  n=3072   base 0
//  j1 Wkvd -> W13T+1536*2048    R=2048 C=576  gx=18  n=1152   base 3072
//  j2 Wqu  -> WquT              R=1536 C=3072 gx=96  n=4608   base 4224
//  j3 Wkvu -> WkvuT             R=512  C=4096 gx=128 n=2048   base 8832
//  j4 Wo   -> WoT               R=2048 C=2048 gx=64  n=4096   base 10880  (total 14976)
__global__ __launch_bounds__(256)
void transpose_all(const float* __restrict__ Wqd, const float* __restrict__ Wkvd,
                   const float* __restrict__ Wqu, const float* __restrict__ Wkvu,
                   const float* __restrict__ Wo,
                   u16* __restrict__ W13T, u16* __restrict__ WquT,
                   u16* __restrict__ WkvuT, u16* __restrict__ WoT) {
  __shared__ u16 tile[32][33];
  int n = blockIdx.x;
  const float* in; u16* out; int R, C, gx, local;
  if (n < 3072)       { in = Wqd;  out = W13T;                        R = 2048; C = 1536; gx = 48;  local = n; }
  else if (n < 4224)  { in = Wkvd; out = W13T + (size_t)1536 * 2048;  R = 2048; C = 576;  gx = 18;  local = n - 3072; }
  else if (n < 8832)  { in = Wqu;  out = WquT;                        R = 1536; C = 3072; gx = 96;  local = n - 4224; }
  else if (n < 10880) { in = Wkvu; out = WkvuT;                       R = 512;  C = 4096; gx = 128; local = n - 8832; }
  else                { in = Wo;   out = WoT;                         R = 2048; C = 2048; gx = 64;  local = n - 10880; }
  int c0 = (local % gx) * 32, r0 = (local / gx) * 32;
  for (int i = threadIdx.y; i < 32; i += 8)
    tile[i][threadIdx.x] = f2b(in[(size_t)(r0 + i) * C + c0 + threadIdx.x]);
  __syncthreads();
  for (int i = threadIdx.y; i < 32; i += 8)
    out[(size_t)(c0 + i) * R + r0 + threadIdx.x] = tile[threadIdx.x][i];
}

// ---------------- MFMA bt-GEMM body: C[.][N] = A[.][K] * BT[N][K]^T ----------------
// 128x128 tile, 4 waves, BK=32 (r7 measured-good).
// LDS unit map (16B units): u = row*4 + (kq ^ ((row>>1)&3)).
// Staging: gld_lds 16B/lane, linear LDS dest, per-lane swizzled global source
//   (4 consecutive lanes = one row's 4 K-octets -> 64B coalesced segments).
// Fragment read: unit (row<<2)|(q^((row>>1)&3)) -> 2-way bank aliasing (free).
// XCD swizzle: bijective chunk per XCD (nwg%8==0 for all grids used).
template<int OUT_BF16>
DEV void gemm_body(const u16* __restrict__ A, const u16* __restrict__ BT, void* __restrict__ Cp,
                   int N, int K, int gx, int nwg, int orig, u16* As, u16* Bs) {
  const int tid = threadIdx.x;
  const int lane = tid & 63;
  const int wave = tid >> 6;
  const int wm = (wave >> 1) * 64;
  const int wn = (wave & 1) * 64;
  const int q = lane >> 4;
  const int l16 = lane & 15;

  const int cpx = nwg >> 3;
  const int swz = (orig & 7) * cpx + (orig >> 3);
  const int bm = (swz / gx) * 128;
  const int bn = (swz % gx) * 128;

  f32x4 zero = {0.f, 0.f, 0.f, 0.f};
  f32x4 acc[4][4];
  #pragma unroll
  for (int i = 0; i < 4; i++)
    #pragma unroll
    for (int j = 0; j < 4; j++) acc[i][j] = zero;

  for (int k0 = 0; k0 < K; k0 += 32) {
    #pragma unroll
    for (int i = 0; i < 2; i++) {
      int jb = i * 256 + wave * 64;      // chunk base, 16B units (wave-uniform)
      int u = jb + lane;
      int row = u >> 2;
      int kq = (u & 3) ^ ((u >> 3) & 3);
      gld16(A + (size_t)(bm + row) * K + k0 + kq * 8, As + jb * 8);
      int rB = bn + row;
      if (rB >= N) rB = N - 1;           // clamp: finite garbage, cols >= N never stored
      gld16(BT + (size_t)rB * K + k0 + kq * 8, Bs + jb * 8);
    }
    __syncthreads();   // vmcnt(0) drained before barrier: staging visible
    bf16x8 af[4], bfr[4];
    #pragma unroll
    for (int t = 0; t < 4; t++) {
      int rowA = wm + t * 16 + l16;
      int rowB = wn + t * 16 + l16;
      int uA = (rowA << 2) | (q ^ ((rowA >> 1) & 3));
      int uB = (rowB << 2) | (q ^ ((rowB >> 1) & 3));
      af[t]  = *reinterpret_cast<const bf16x8*>(As + uA * 8);
      bfr[t] = *reinterpret_cast<const bf16x8*>(Bs + uB * 8);
    }
    #pragma unroll
    for (int mt = 0; mt < 4; mt++)
      #pragma unroll
      for (int nt = 0; nt < 4; nt++)
        acc[mt][nt] = __builtin_amdgcn_mfma_f32_16x16x32_bf16(af[mt], bfr[nt], acc[mt][nt], 0, 0, 0);
    __syncthreads();
  }

  float* Cf = (float*)Cp;
  u16* Cb = (u16*)Cp;
  #pragma unroll
  for (int mt = 0; mt < 4; mt++) {
    #pragma unroll
    for (int nt = 0; nt < 4; nt++) {
      int col = bn + wn + nt * 16 + l16;
      if (col < N) {
        int row0 = bm + wm + mt * 16 + q * 4;
        #pragma unroll
        for (int r = 0; r < 4; r++) {
          size_t idx = (size_t)(row0 + r) * N + col;
          float v = acc[mt][nt][r];
          if (OUT_BF16) Cb[idx] = f2b(v); else Cf[idx] = v;
        }
      }
    }
  }
}

template<int OUT_BF16>
__global__ __launch_bounds__(256)
void gemm_bt(const u16* __restrict__ A, const u16* __restrict__ BT, void* __restrict__ Cp,
             int N, int K) {
  __shared__ __attribute__((aligned(16))) u16 As[4096];
  __shared__ __attribute__((aligned(16))) u16 Bs[4096];
  const int gx = gridDim.x;
  const int nwg = gx * gridDim.y;
  const int orig = blockIdx.y * gx + blockIdx.x;
  gemm_body<OUT_BF16>(A, BT, Cp, N, K, gx, nwg, orig, As, Bs);
}

// fused independent up-projections: blocks 0..767 = q-up (4096x3072 K=1536),
// 768..1791 = kv-up (4096x4096 K=512). Both sub-grids %8==0 -> per-job XCD swizzle.
__global__ __launch_bounds__(256)
void gemm_up2(const u16* __restrict__ qlat, const u16* __restrict__ WquT, u16* __restrict__ q2,
              const u16* __restrict__ kvl, const u16* __restrict__ WkvuT, u16* __restrict__ kvb) {
  __shared__ __attribute__((aligned(16))) u16 As[4096];
  __shared__ __attribute__((aligned(16))) u16 Bs[4096];
  int n = blockIdx.x;
  if (n < 768) gemm_body<1>(qlat, WquT, q2, 3072, 1536, 24, 768, n, As, Bs);
  else         gemm_body<1>(kvl, WkvuT, kvb, 4096, 512, 32, 1024, n - 768, As, Bs);
}

// ---------------- fused norm/split: blocks 0..4095 rmsnorm(q-latent), 4096..8191 kv-split ----------------
__global__ __launch_bounds__(256)
void norm_split(const float* __restrict__ t13, const float* __restrict__ fc, const float* __restrict__ fs,
                u16* __restrict__ qlat, u16* __restrict__ kvl, u16* __restrict__ krope) {
  __shared__ float red[4];
  __shared__ float s_scale;
  int lane = threadIdx.x & 63, wid = threadIdx.x >> 6;
  if (blockIdx.x < 4096) {
    int row = blockIdx.x;
    const float* x = t13 + (size_t)row * 2112;
    float ss = 0.f;
    for (int i = threadIdx.x; i < 1536; i += 256) { float v = x[i]; ss += v * v; }
    ss = waveReduceSum(ss);
    if (lane == 0) red[wid] = ss;
    __syncthreads();
    if (threadIdx.x == 0)
      s_scale = rsqrtf((red[0] + red[1] + red[2] + red[3]) * (1.0f / 1536.0f) + 1e-5f);
    __syncthreads();
    float sc = s_scale;
    u16* o = qlat + (size_t)row * 1536;
    for (int i = threadIdx.x; i < 1536; i += 256) o[i] = f2b(x[i] * sc);
  } else {
    int row = blockIdx.x - 4096;
    int s = row & 2047;
    const float* x = t13 + (size_t)row * 2112 + 1536;
    float ss = 0.f;
    for (int i = threadIdx.x; i < 512; i += 256) { float v = x[i]; ss += v * v; }
    ss = waveReduceSum(ss);
    if (lane == 0) red[wid] = ss;
    __syncthreads();
    if (threadIdx.x == 0)
      s_scale = rsqrtf((red[0] + red[1] + red[2] + red[3]) * (1.0f / 512.0f) + 1e-5f);
    __syncthreads();
    float sc = s_scale;
    for (int i = threadIdx.x; i < 512; i += 256) kvl[(size_t)row * 512 + i] = f2b(x[i] * sc);
    if (threadIdx.x < 32) {
      int i = threadIdx.x;
      float cc = fc[s * 32 + i], sn = fs[s * 32 + i];
      float x0 = x[512 + 2 * i], x1 = x[512 + 2 * i + 1];
      krope[(size_t)row * 64 + 2 * i]     = f2b(x0 * cc - x1 * sn);
      krope[(size_t)row * 64 + 2 * i + 1] = f2b(x0 * sn + x1 * cc);
    }
  }
}

// ---------------- rope + pack Q, PRESCALED by log2e/sqrt(192) ----------------
// exp2-domain prescale: raw scores come out *log2e, so softmax uses exp2 directly.
__global__ __launch_bounds__(256)
void rope_pack_q(const u16* __restrict__ q2, const float* __restrict__ fc, const float* __restrict__ fs,
                 u16* __restrict__ Q) {
  const float scale = 0.10411756711f;  // (1/sqrt(192)) * log2(e)
  int bs = blockIdx.x;
  int b = bs >> 11, s = bs & 2047;
  __shared__ float c[32], sn[32];
  if (threadIdx.x < 32) {
    c[threadIdx.x] = fc[s * 32 + threadIdx.x];
    sn[threadIdx.x] = fs[s * 32 + threadIdx.x];
  }
  __syncthreads();
  const u16* qrow = q2 + (size_t)bs * 3072;
  for (int t = threadIdx.x; t < 512; t += 256) {
    int h = t >> 5, i = t & 31;
    float x0 = b2f(qrow[h * 192 + 128 + 2 * i]);
    float x1 = b2f(qrow[h * 192 + 128 + 2 * i + 1]);
    size_t base = ((size_t)(b * 16 + h) * 2048 + s) * 192;
    Q[base + 2 * i]     = f2b((x0 * c[i] - x1 * sn[i]) * scale);
    Q[base + 2 * i + 1] = f2b((x0 * sn[i] + x1 * c[i]) * scale);
  }
  for (int t = threadIdx.x; t < 2048; t += 256) {
    int h = t >> 7, j = t & 127;
    Q[((size_t)(b * 16 + h) * 2048 + s) * 192 + 64 + j] = f2b(b2f(qrow[h * 192 + j]) * scale);
  }
}

// ---------------- assemble K chunked + V transposed chunked ----------------
// Kc[bh][kq 0..23][s 2048][8]  (dims kq*8..+7 of [rope64|nope128])
// Vt[bh][ks 0..255][dv 128][8] (keys ks*8..+7)
__global__ __launch_bounds__(256)
void assemble_kv2(const u16* __restrict__ kvb, const u16* __restrict__ krope,
                  u16* __restrict__ Kc, u16* __restrict__ Vt) {
  int ks = blockIdx.x;   // 0..255
  int bh = blockIdx.y;   // 0..31
  int b = bh >> 4, h = bh & 15;
  int t = threadIdx.x;
  if (t < 192) {
    int kq = t >> 3, sl = t & 7;
    int s = ks * 8 + sl;
    size_t bs = (size_t)(b * 2048 + s);
    uint4 v;
    if (kq < 8) v = *reinterpret_cast<const uint4*>(krope + bs * 64 + kq * 8);
    else        v = *reinterpret_cast<const uint4*>(kvb + bs * 4096 + h * 128 + (kq - 8) * 8);
    *reinterpret_cast<uint4*>(Kc + (((size_t)bh * 24 + kq) * 2048 + s) * 8) = v;
  }
  if (t < 128) {
    int dv = t;
    u16 tmp[8];
    #pragma unroll
    for (int j = 0; j < 8; j++) {
      int s = ks * 8 + j;
      tmp[j] = kvb[(size_t)(b * 2048 + s) * 4096 + 2048 + h * 128 + dv];
    }
    *reinterpret_cast<uint4*>(Vt + (((size_t)bh * 256 + ks) * 128 + dv) * 8) = *reinterpret_cast<uint4*>(tmp);
  }
}

// ---------------- MFMA flash attention v8b ----------------
// v7 structure (measured 78.4): 64 q/wave, 512 blocks, balanced pairs {t,31-t},
// XCD-local bh, K-dbuf counted vmcnt, l via ones-fragment.
// Softmax trim: scores arrive in exp2 domain (Q prescaled by log2e) -> single
// compiler-emitted v_exp_f32 (__builtin_amdgcn_exp2f; hazards handled); native
// RTNE bf16 cast; wave-uniform causal-mask hoist.
__global__ __launch_bounds__(256, 2)
void flash_attn8(const u16* __restrict__ Q, const u16* __restrict__ Kc,
                 const u16* __restrict__ Vt, u16* __restrict__ O) {
  __shared__ __attribute__((aligned(16))) u16 Ks[2][24 * 64 * 8];  // 49 KB dbuf [kq][key][8]
  __shared__ __attribute__((aligned(16))) u16 Vs[8 * 128 * 8];     // 16 KB [kc][dv][8]
  __shared__ __attribute__((aligned(16))) u16 Ps[4 * 16 * 72];     // 9 KB per-wave P, stride 72

  const int blk = blockIdx.x;
  const int bh = ((blk & 7) << 2) | (blk >> 7);
  const int tpair = (blk >> 3) & 15;
  const int b = bh >> 4, h = bh & 15;
  const int tid = threadIdx.x, lane = tid & 63, wave = tid >> 6;
  const int quad = lane >> 4, l16 = lane & 15;
  u16* PsW = Ps + wave * 16 * 72;

  // constant ones-column B-fragment: B[n][k] = (n==0) ? 1 : 0
  bf16x8 onesf;
  #pragma unroll
  for (int j = 0; j < 8; j++) onesf[j] = (l16 == 0) ? (__bf16)1.0f : (__bf16)0.0f;

  auto stageK = [&](u16* KsB, int kk) {
    #pragma unroll
    for (int ii = 0; ii < 6; ii++) {
      int kq = wave * 6 + ii;
      gld16(Kc + (((size_t)bh * 24 + kq) * 2048 + kk + lane) * 8, KsB + kq * 64 * 8);
    }
  };
  auto stageV = [&](int kk) {
    #pragma unroll
    for (int jj = 0; jj < 4; jj++) {
      int vc = wave * 4 + jj, kc = vc >> 1, dvh = vc & 1;
      gld16(Vt + (((size_t)bh * 256 + (kk >> 3) + kc) * 128 + dvh * 64 + lane) * 8,
            Vs + (kc * 128 + dvh * 64) * 8);
    }
  };

  for (int phase = 0; phase < 2; phase++) {
    const int qt = phase == 0 ? tpair : 31 - tpair;
    const int q0 = qt * 64;
    const int nk = (qt + 1) * 64;

    bf16x8 qf[6];
    {
      int qrow = q0 + wave * 16 + l16;
      const u16* qp = Q + ((size_t)bh * 2048 + qrow) * 192 + quad * 8;
      #pragma unroll
      for (int kc = 0; kc < 6; kc++)
        qf[kc] = *reinterpret_cast<const bf16x8*>(qp + kc * 32);
    }

    f32x4 zero = {0.f, 0.f, 0.f, 0.f};
    f32x4 oacc[9];
    #pragma unroll
    for (int nt = 0; nt < 9; nt++) oacc[nt] = zero;

    for (int k0 = 0; k0 < nk; k0 += 64) {
      const int cur = (k0 >> 6) & 1;
      const bool hasnext = (k0 + 64 < nk);

      // BAR_a: all waves finished prev PV (Vs free) and prev QK^T (Ks[cur^1] free)
      __builtin_amdgcn_s_barrier();
      __builtin_amdgcn_sched_barrier(0);
      if (k0 == 0) stageK(Ks[0], 0);     // first K (oldest in FIFO -> retired by vmcnt(10))
      stageV(k0);
      if (hasnext) {
        stageK(Ks[cur ^ 1], k0 + 64);    // prefetch next K; stays in flight past BAR_b
        asm volatile("s_waitcnt vmcnt(10)" ::: "memory");  // cur K done; V+Knext flying
      } else {
        asm volatile("s_waitcnt vmcnt(4)" ::: "memory");   // cur K done; V flying
      }
      __builtin_amdgcn_sched_barrier(0);
      __builtin_amdgcn_s_barrier();      // BAR_b: K(cur) visible to all waves
      __builtin_amdgcn_sched_barrier(0);

      const u16* KsC = Ks[cur];

      // QK^T (Q pre-scaled by log2e/sqrt(192))
      f32x4 sacc[4];
      #pragma unroll
      for (int nt = 0; nt < 4; nt++) sacc[nt] = zero;
      #pragma unroll
      for (int kc = 0; kc < 6; kc++) {
        #pragma unroll
        for (int nt = 0; nt < 4; nt++) {
          bf16x8 kb = *reinterpret_cast<const bf16x8*>(KsC + ((kc * 4 + quad) * 64 + nt * 16 + l16) * 8);
          sacc[nt] = __builtin_amdgcn_mfma_f32_16x16x32_bf16(qf[kc], kb, sacc[nt], 0, 0, 0);
        }
      }

      // exp2-domain softmax: P = 2^s (masked); wave-uniform mask hoist
      if (k0 + 63 <= q0 + wave * 16) {
        // fully below diagonal for every row of this wave: no masking
        #pragma unroll
        for (int r = 0; r < 4; r++) {
          #pragma unroll
          for (int nt = 0; nt < 4; nt++) {
            float p = EXP2(sacc[nt][r]);
            PsW[(quad * 4 + r) * 72 + nt * 16 + l16] = f2b_hw(p);
          }
        }
      } else {
        #pragma unroll
        for (int r = 0; r < 4; r++) {
          int qrow_g = q0 + wave * 16 + quad * 4 + r;
          #pragma unroll
          for (int nt = 0; nt < 4; nt++) {
            int key = k0 + nt * 16 + l16;
            float e = EXP2(sacc[nt][r]);
            float p = (key <= qrow_g) ? e : 0.f;
            PsW[(quad * 4 + r) * 72 + nt * 16 + l16] = f2b_hw(p);
          }
        }
      }

      if (hasnext) asm volatile("s_waitcnt vmcnt(6)" ::: "memory");  // V done; Knext flying
      else         asm volatile("s_waitcnt vmcnt(0)" ::: "memory");
      __builtin_amdgcn_sched_barrier(0);
      __builtin_amdgcn_s_barrier();      // BAR_c: V(cur) visible to all waves
      __builtin_amdgcn_sched_barrier(0);

      // PV (+ l via ones-fragment): P from wave-private LDS (A-layout)
      #pragma unroll
      for (int kcp = 0; kcp < 2; kcp++) {
        bf16x8 pa = *reinterpret_cast<const bf16x8*>(PsW + l16 * 72 + kcp * 32 + quad * 8);
        #pragma unroll
        for (int nt = 0; nt < 8; nt++) {
          bf16x8 vb = *reinterpret_cast<const bf16x8*>(Vs + ((kcp * 4 + quad) * 128 + nt * 16 + l16) * 8);
          oacc[nt] = __builtin_amdgcn_mfma_f32_16x16x32_bf16(pa, vb, oacc[nt], 0, 0, 0);
        }
        oacc[8] = __builtin_amdgcn_mfma_f32_16x16x32_bf16(pa, onesf, oacc[8], 0, 0, 0);
      }
    }

    // epilogue: l sits in oacc[8][r] at l16==0 of each quad; broadcast within quad
    #pragma unroll
    for (int r = 0; r < 4; r++) {
      float l = __shfl(oacc[8][r], lane & 48, 64);
      float inv = 1.0f / l;
      int s = q0 + wave * 16 + quad * 4 + r;
      #pragma unroll
      for (int nt = 0; nt < 8; nt++)
        O[((size_t)b * 2048 + s) * 2048 + h * 128 + nt * 16 + l16] = f2b(oacc[nt][r] * inv);
    }
  }
}

// ---------------- launch ----------------
extern "C" void kernel_launch(void* const* d_in, const int* in_sizes, int n_in,
                              void* d_out, int out_size, void* d_ws, size_t ws_size,
                              hipStream_t stream) {
  (void)in_sizes; (void)n_in; (void)out_size; (void)ws_size;
  const float* hs   = (const float*)d_in[0];
  const float* fc   = (const float*)d_in[2];
  const float* fs   = (const float*)d_in[3];
  const float* Wqd  = (const float*)d_in[4];
  const float* Wkvd = (const float*)d_in[5];
  const float* Wqu  = (const float*)d_in[6];
  const float* Wkvu = (const float*)d_in[7];
  const float* Wo   = (const float*)d_in[8];

  char* ws = (char*)d_ws;
  size_t off = 0;
  auto alloc = [&](size_t bytes) { size_t o = off; off += (bytes + 255) & ~(size_t)255; return o; };
  const size_t oHS   = alloc(16777216);  // hs_bf bf16 [4096][2048]
  const size_t oRA   = alloc(16777216);  // Vt bf16 [32][256][128][8]
  const size_t oRB   = alloc(25165824);  // q2 bf16 [4096][3072] -> Kc bf16
  const size_t oRC   = alloc(12582912);  // qlat bf16 [4096][1536]
  const size_t oRD   = alloc(25165824);  // Q bf16 [B*H][S][192]
  const size_t oRE   = alloc(34603008);  // t13 f32 [4096][2112] -> kvb bf16 [4096][4096] -> attn_out
  const size_t oKVL  = alloc(4194304);   // kvl bf16 [4096][512]
  const size_t oKR   = alloc(524288);    // krope bf16 [4096][64]
  const size_t oW13T  = alloc(8650752);  // [2112][2048] bf16 (WqdT rows 0..1535, WkvdT rows 1536..)
  const size_t oWquT  = alloc(9437184);
  const size_t oWkvuT = alloc(4194304);
  const size_t oWoT   = alloc(8388608);

  u16* hs_bf = (u16*)(ws + oHS);
  u16* Vt   = (u16*)(ws + oRA);
  u16* q2   = (u16*)(ws + oRB);
  u16* Kc   = (u16*)(ws + oRB);
  u16* qlat = (u16*)(ws + oRC);
  u16* Qb   = (u16*)(ws + oRD);
  float* t13 = (float*)(ws + oRE);
  u16* kvb  = (u16*)(ws + oRE);
  u16* attn_out = (u16*)(ws + oRE);
  u16* kvl  = (u16*)(ws + oKVL);
  u16* krope = (u16*)(ws + oKR);
  u16* W13T  = (u16*)(ws + oW13T);
  u16* WquT  = (u16*)(ws + oWquT);
  u16* WkvuT = (u16*)(ws + oWkvuT);
  u16* WoT   = (u16*)(ws + oWoT);

  cvt_f32_bf16<<<8192, 256, 0, stream>>>(hs, hs_bf, 2097152);
  transpose_all<<<14976, dim3(32, 8), 0, stream>>>(Wqd, Wkvd, Wqu, Wkvu, Wo, W13T, WquT, WkvuT, WoT);

  // fused down-projections: t13 = hs @ [Wq_down | Wkv_down]
  gemm_bt<0><<<dim3(17, 32), 256, 0, stream>>>(hs_bf, W13T, t13, 2112, 2048);
  // fused rmsnorm(q-latent) + kv split
  norm_split<<<8192, 256, 0, stream>>>(t13, fc, fs, qlat, kvl, krope);
  // fused independent up-projections (concurrent): q2 and kvb
  gemm_up2<<<1792, 256, 0, stream>>>(qlat, WquT, q2, kvl, WkvuT, kvb);
  // rope+pack Q (reads q2 BEFORE Kc overwrites the same buffer in assemble_kv2)
  rope_pack_q<<<4096, 256, 0, stream>>>(q2, fc, fs, Qb);
  assemble_kv2<<<dim3(256, 32), 256, 0, stream>>>(kvb, krope, Kc, Vt);
  // attention (v7 structure + exp2 softmax trim, compiler-emitted exp)
  flash_attn8<<<dim3(512), 256, 0, stream>>>(Qb, Kc, Vt, attn_out);
  // output projection (fp32 out)
  gemm_bt<0><<<dim3(16, 32), 256, 0, stream>>>(attn_out, WoT, (float*)d_out, 2048, 2048);
}

// Round 12
// 442.078 us; speedup vs baseline: 1.1340x; 1.0094x over previous
//
#include <hip/hip_runtime.h>
#include <math.h>

// DeepSeekV3 MLA forward, MI355X gfx950.
// I/O fp32; internal math bf16 MFMA.
// GEMMs r10: gemm256 -- 256x256 tile, 8 waves (512 thr), BK=32, TRI-buffered LDS,
//            stage-ahead-by-2 with counted vmcnt(4) at K-step boundary (never 0
//            mid-loop), ONE barrier/step, 2 setprio MFMA phases with staging
//            interleaved. XOR-unit LDS map kept (0 bank conflicts measured r10).
//            Applied to down-proj (N-clamped), fused up2, o-proj.
// Flash v8b (measured, part of 446us): v7 K-dbuf counted-vmcnt structure + exp2
//            softmax (builtin), RTNE cast, wave-uniform mask hoist.
// Glue r8 (measured): transpose_all, norm_split, fused launches.
// B=2 S=2048 D=2048 H=16 NOPE=128 ROPE=64 DV=128 DQK=192 QLR=1536 KVLR=512

typedef unsigned short u16;
typedef __attribute__((ext_vector_type(8))) __bf16 bf16x8;
typedef __attribute__((ext_vector_type(4))) float f32x4;

#define DEV static __device__ __forceinline__

#if __has_builtin(__builtin_amdgcn_exp2f)
#define EXP2(x) __builtin_amdgcn_exp2f(x)
#else
#define EXP2(x) exp2f(x)
#endif

DEV float b2f(u16 v) { return __uint_as_float(((unsigned int)v) << 16); }
DEV u16 f2b(float f) {
  unsigned int u = __float_as_uint(f);
  u += 0x7fffu + ((u >> 16) & 1u);   // round-to-nearest-even
  return (u16)(u >> 16);
}
// native RTNE cvt -- compiler-generated, 1 instr, hazard-safe
DEV u16 f2b_hw(float f) {
  __bf16 h = (__bf16)f;
  u16 r;
  __builtin_memcpy(&r, &h, 2);
  return r;
}

DEV float waveReduceSum(float v) {
  #pragma unroll
  for (int o = 32; o > 0; o >>= 1) v += __shfl_down(v, o, 64);
  return v;
}

// async global->LDS, 16B per lane; LDS dest = wave-uniform base + lane*16
DEV void gld16(const u16* g, u16* l) {
  __builtin_amdgcn_global_load_lds((const __attribute__((address_space(1))) void*)g,
                                   (__attribute__((address_space(3))) void*)l, 16, 0, 0);
}

// ---------------- convert fp32 -> bf16 (flat) ----------------
__global__ __launch_bounds__(256)
void cvt_f32_bf16(const float* __restrict__ in, u16* __restrict__ out, int n4) {
  int i = blockIdx.x * 256 + threadIdx.x;
  if (i < n4) {
    float4 v = reinterpret_cast<const float4*>(in)[i];
    ushort4 o;
    o.x = f2b(v.x); o.y = f2b(v.y); o.z = f2b(v.z); o.w = f2b(v.w);
    reinterpret_cast<ushort4*>(out)[i] = o;
  }
}

// ---------------- fused transpose+convert of all 5 weights ----------------
__global__ __launch_bounds__(256)
void transpose_all(const float* __restrict__ Wqd, const float* __restrict__ Wkvd,
                   const float* __restrict__ Wqu, const float* __restrict__ Wkvu,
                   const float* __restrict__ Wo,
                   u16* __restrict__ W13T, u16* __restrict__ WquT,
                   u16* __restrict__ WkvuT, u16* __restrict__ WoT) {
  __shared__ u16 tile[32][33];
  int n = blockIdx.x;
  const float* in; u16* out; int R, C, gx, local;
  if (n < 3072)       { in = Wqd;  out = W13T;                        R = 2048; C = 1536; gx = 48;  local = n; }
  else if (n < 4224)  { in = Wkvd; out = W13T + (size_t)1536 * 2048;  R = 2048; C = 576;  gx = 18;  local = n - 3072; }
  else if (n < 8832)  { in = Wqu;  out = WquT;                        R = 1536; C = 3072; gx = 96;  local = n - 4224; }
  else if (n < 10880) { in = Wkvu; out = WkvuT;                       R = 512;  C = 4096; gx = 128; local = n - 8832; }
  else                { in = Wo;   out = WoT;                         R = 2048; C = 2048; gx = 64;  local = n - 10880; }
  int c0 = (local % gx) * 32, r0 = (local / gx) * 32;
  for (int i = threadIdx.y; i < 32; i += 8)
    tile[i][threadIdx.x] = f2b(in[(size_t)(r0 + i) * C + c0 + threadIdx.x]);
  __syncthreads();
  for (int i = threadIdx.y; i < 32; i += 8)
    out[(size_t)(c0 + i) * R + r0 + threadIdx.x] = tile[threadIdx.x][i];
}

// ---------------- gemm256 body: C[.][N] = A[.][K] * BT[N][K]^T ----------------
// 256x256 tile, 8 waves (2M x 4N), per-wave 128x64 output (8x4 frags, 128 acc VGPR).
// BK=32; TRI-buffered LDS (3 x 16KB per operand = 96KB). Pipeline:
//   prologue: stage(0), stage(1).
//   step t: vmcnt(4) [retire stage t; keep stage t+1 flying] -> barrier [publish
//   buf t%3] -> phase0 {read B frags + A mt0-3, issue stageA(t+2), 16 MFMA} ->
//   phase1 {read A mt4-7, issue stageB(t+2), 16 MFMA}.
// Loads for step t+2 issued ~2 K-steps before their wait -> latency fully hidden;
// vmcnt never drains to 0 mid-loop (T4). One barrier per step: each wave's own
// vmcnt before the join certifies its staged data; the join also orders all reads
// of buf[t%3] before step t+1's stage into buf[(t+3)%3] == buf[t%3].
// LDS unit map (16B units): u = row*4 + (kq ^ ((row>>1)&3)) -- 64B-coalesced
// staging sources, 2-way (free) read aliasing. 0 bank conflicts measured (r10).
template<int OUT_BF16>
DEV void gemm256_body(const u16* __restrict__ A, const u16* __restrict__ BT, void* __restrict__ Cp,
                      int N, int K, int gx, int nwg, int orig,
                      u16 (*As)[8192], u16 (*Bs)[8192]) {
  const int tid = threadIdx.x;           // 0..511
  const int lane = tid & 63;
  const int wave = tid >> 6;             // 0..7
  const int wm = (wave >> 2) * 128;      // 0 / 128
  const int wn = (wave & 3) * 64;        // 0 / 64 / 128 / 192
  const int q = lane >> 4;
  const int l16 = lane & 15;

  // bijective XCD-chunk swizzle (nwg % 8 == 0 at every call site)
  const int cpx = nwg >> 3;
  const int swz = (orig & 7) * cpx + (orig >> 3);
  const int bm = (swz / gx) * 256;
  const int bn = (swz % gx) * 256;

  auto stageA = [&](int buf, int k0) {
    #pragma unroll
    for (int i = 0; i < 2; i++) {
      int ub = i * 512 + wave * 64;      // wave-uniform chunk base (16B units)
      int u = ub + lane;
      int row = u >> 2;
      int kq = (u & 3) ^ ((u >> 3) & 3);
      gld16(A + (size_t)(bm + row) * K + k0 + kq * 8, As[buf] + ub * 8);
    }
  };
  auto stageB = [&](int buf, int k0) {
    #pragma unroll
    for (int i = 0; i < 2; i++) {
      int ub = i * 512 + wave * 64;
      int u = ub + lane;
      int row = u >> 2;
      int kq = (u & 3) ^ ((u >> 3) & 3);
      int rB = bn + row;
      if (rB >= N) rB = N - 1;           // clamp: finite garbage, cols >= N never stored
      gld16(BT + (size_t)rB * K + k0 + kq * 8, Bs[buf] + ub * 8);
    }
  };

  f32x4 zero = {0.f, 0.f, 0.f, 0.f};
  f32x4 acc[8][4];
  #pragma unroll
  for (int i = 0; i < 8; i++)
    #pragma unroll
    for (int j = 0; j < 4; j++) acc[i][j] = zero;

  const int nt = K >> 5;
  stageA(0, 0);  stageB(0, 0);
  stageA(1, 32); stageB(1, 32);

  for (int t = 0; t < nt; ++t) {
    const int cur = t % 3;
    if (t + 1 < nt) asm volatile("s_waitcnt vmcnt(4)" ::: "memory");
    else            asm volatile("s_waitcnt vmcnt(0)" ::: "memory");
    __builtin_amdgcn_sched_barrier(0);
    __builtin_amdgcn_s_barrier();        // publish buf[cur]; orders prior reads vs next stages
    __builtin_amdgcn_sched_barrier(0);

    const u16* Ab = As[cur];
    const u16* Bb = Bs[cur];
    const int nxt = (t + 2) % 3;
    const bool pre = (t + 2) < nt;
    const int kpre = (t + 2) * 32;

    // phase 0: B frags (live both phases) + A frags mt0-3; prefetch next A-tile
    bf16x8 bfr[4], af[4];
    #pragma unroll
    for (int j = 0; j < 4; j++) {
      int rowB = wn + j * 16 + l16;
      bfr[j] = *reinterpret_cast<const bf16x8*>(Bb + (((rowB) << 2) | (q ^ ((rowB >> 1) & 3))) * 8);
      int rowA = wm + j * 16 + l16;
      af[j] = *reinterpret_cast<const bf16x8*>(Ab + (((rowA) << 2) | (q ^ ((rowA >> 1) & 3))) * 8);
    }
    if (pre) stageA(nxt, kpre);
    __builtin_amdgcn_s_setprio(1);
    #pragma unroll
    for (int mt = 0; mt < 4; mt++)
      #pragma unroll
      for (int j = 0; j < 4; j++)
        acc[mt][j] = __builtin_amdgcn_mfma_f32_16x16x32_bf16(af[mt], bfr[j], acc[mt][j], 0, 0, 0);
    __builtin_amdgcn_s_setprio(0);

    // phase 1: A frags mt4-7; prefetch next B-tile
    bf16x8 af2[4];
    #pragma unroll
    for (int j = 0; j < 4; j++) {
      int rowA = wm + (j + 4) * 16 + l16;
      af2[j] = *reinterpret_cast<const bf16x8*>(Ab + (((rowA) << 2) | (q ^ ((rowA >> 1) & 3))) * 8);
    }
    if (pre) stageB(nxt, kpre);
    __builtin_amdgcn_s_setprio(1);
    #pragma unroll
    for (int mt = 0; mt < 4; mt++)
      #pragma unroll
      for (int j = 0; j < 4; j++)
        acc[mt + 4][j] = __builtin_amdgcn_mfma_f32_16x16x32_bf16(af2[mt], bfr[j], acc[mt + 4][j], 0, 0, 0);
    __builtin_amdgcn_s_setprio(0);
  }

  float* Cf = (float*)Cp;
  u16* Cb = (u16*)Cp;
  #pragma unroll
  for (int mt = 0; mt < 8; mt++) {
    #pragma unroll
    for (int j = 0; j < 4; j++) {
      int col = bn + wn + j * 16 + l16;
      if (col < N) {
        int row0 = bm + wm + mt * 16 + q * 4;
        #pragma unroll
        for (int r = 0; r < 4; r++) {
          size_t idx = (size_t)(row0 + r) * N + col;
          float v = acc[mt][j][r];
          if (OUT_BF16) Cb[idx] = f2b(v); else Cf[idx] = v;
        }
      }
    }
  }
}

template<int OUT_BF16>
__global__ __launch_bounds__(512, 1)
void gemm256(const u16* __restrict__ A, const u16* __restrict__ BT, void* __restrict__ Cp,
             int N, int K) {
  __shared__ __attribute__((aligned(16))) u16 As[3][8192];
  __shared__ __attribute__((aligned(16))) u16 Bs[3][8192];
  const int gx = gridDim.x;
  const int nwg = gx * gridDim.y;
  const int orig = blockIdx.y * gx + blockIdx.x;
  gemm256_body<OUT_BF16>(A, BT, Cp, N, K, gx, nwg, orig, As, Bs);
}

// fused independent up-projections: blocks 0..191 = q-up (4096x3072 K=1536, 16x12),
// 192..447 = kv-up (4096x4096 K=512, 16x16). Long jobs first (LPT). Both %8==0.
__global__ __launch_bounds__(512, 1)
void gemm_up2(const u16* __restrict__ qlat, const u16* __restrict__ WquT, u16* __restrict__ q2,
              const u16* __restrict__ kvl, const u16* __restrict__ WkvuT, u16* __restrict__ kvb) {
  __shared__ __attribute__((aligned(16))) u16 As[3][8192];
  __shared__ __attribute__((aligned(16))) u16 Bs[3][8192];
  int n = blockIdx.x;
  if (n < 192) gemm256_body<1>(qlat, WquT, q2, 3072, 1536, 12, 192, n, As, Bs);
  else         gemm256_body<1>(kvl, WkvuT, kvb, 4096, 512, 16, 256, n - 192, As, Bs);
}

// ---------------- fused norm/split: blocks 0..4095 rmsnorm(q-latent), 4096..8191 kv-split ----------------
__global__ __launch_bounds__(256)
void norm_split(const float* __restrict__ t13, const float* __restrict__ fc, const float* __restrict__ fs,
                u16* __restrict__ qlat, u16* __restrict__ kvl, u16* __restrict__ krope) {
  __shared__ float red[4];
  __shared__ float s_scale;
  int lane = threadIdx.x & 63, wid = threadIdx.x >> 6;
  if (blockIdx.x < 4096) {
    int row = blockIdx.x;
    const float* x = t13 + (size_t)row * 2112;
    float ss = 0.f;
    for (int i = threadIdx.x; i < 1536; i += 256) { float v = x[i]; ss += v * v; }
    ss = waveReduceSum(ss);
    if (lane == 0) red[wid] = ss;
    __syncthreads();
    if (threadIdx.x == 0)
      s_scale = rsqrtf((red[0] + red[1] + red[2] + red[3]) * (1.0f / 1536.0f) + 1e-5f);
    __syncthreads();
    float sc = s_scale;
    u16* o = qlat + (size_t)row * 1536;
    for (int i = threadIdx.x; i < 1536; i += 256) o[i] = f2b(x[i] * sc);
  } else {
    int row = blockIdx.x - 4096;
    int s = row & 2047;
    const float* x = t13 + (size_t)row * 2112 + 1536;
    float ss = 0.f;
    for (int i = threadIdx.x; i < 512; i += 256) { float v = x[i]; ss += v * v; }
    ss = waveReduceSum(ss);
    if (lane == 0) red[wid] = ss;
    __syncthreads();
    if (threadIdx.x == 0)
      s_scale = rsqrtf((red[0] + red[1] + red[2] + red[3]) * (1.0f / 512.0f) + 1e-5f);
    __syncthreads();
    float sc = s_scale;
    for (int i = threadIdx.x; i < 512; i += 256) kvl[(size_t)row * 512 + i] = f2b(x[i] * sc);
    if (threadIdx.x < 32) {
      int i = threadIdx.x;
      float cc = fc[s * 32 + i], sn = fs[s * 32 + i];
      float x0 = x[512 + 2 * i], x1 = x[512 + 2 * i + 1];
      krope[(size_t)row * 64 + 2 * i]     = f2b(x0 * cc - x1 * sn);
      krope[(size_t)row * 64 + 2 * i + 1] = f2b(x0 * sn + x1 * cc);
    }
  }
}

// ---------------- rope + pack Q, PRESCALED by log2e/sqrt(192) ----------------
__global__ __launch_bounds__(256)
void rope_pack_q(const u16* __restrict__ q2, const float* __restrict__ fc, const float* __restrict__ fs,
                 u16* __restrict__ Q) {
  const float scale = 0.10411756711f;  // (1/sqrt(192)) * log2(e)
  int bs = blockIdx.x;
  int b = bs >> 11, s = bs & 2047;
  __shared__ float c[32], sn[32];
  if (threadIdx.x < 32) {
    c[threadIdx.x] = fc[s * 32 + threadIdx.x];
    sn[threadIdx.x] = fs[s * 32 + threadIdx.x];
  }
  __syncthreads();
  const u16* qrow = q2 + (size_t)bs * 3072;
  for (int t = threadIdx.x; t < 512; t += 256) {
    int h = t >> 5, i = t & 31;
    float x0 = b2f(qrow[h * 192 + 128 + 2 * i]);
    float x1 = b2f(qrow[h * 192 + 128 + 2 * i + 1]);
    size_t base = ((size_t)(b * 16 + h) * 2048 + s) * 192;
    Q[base + 2 * i]     = f2b((x0 * c[i] - x1 * sn[i]) * scale);
    Q[base + 2 * i + 1] = f2b((x0 * sn[i] + x1 * c[i]) * scale);
  }
  for (int t = threadIdx.x; t < 2048; t += 256) {
    int h = t >> 7, j = t & 127;
    Q[((size_t)(b * 16 + h) * 2048 + s) * 192 + 64 + j] = f2b(b2f(qrow[h * 192 + j]) * scale);
  }
}

// ---------------- assemble K chunked + V transposed chunked ----------------
__global__ __launch_bounds__(256)
void assemble_kv2(const u16* __restrict__ kvb, const u16* __restrict__ krope,
                  u16* __restrict__ Kc, u16* __restrict__ Vt) {
  int ks = blockIdx.x;   // 0..255
  int bh = blockIdx.y;   // 0..31
  int b = bh >> 4, h = bh & 15;
  int t = threadIdx.x;
  if (t < 192) {
    int kq = t >> 3, sl = t & 7;
    int s = ks * 8 + sl;
    size_t bs = (size_t)(b * 2048 + s);
    uint4 v;
    if (kq < 8) v = *reinterpret_cast<const uint4*>(krope + bs * 64 + kq * 8);
    else        v = *reinterpret_cast<const uint4*>(kvb + bs * 4096 + h * 128 + (kq - 8) * 8);
    *reinterpret_cast<uint4*>(Kc + (((size_t)bh * 24 + kq) * 2048 + s) * 8) = v;
  }
  if (t < 128) {
    int dv = t;
    u16 tmp[8];
    #pragma unroll
    for (int j = 0; j < 8; j++) {
      int s = ks * 8 + j;
      tmp[j] = kvb[(size_t)(b * 2048 + s) * 4096 + 2048 + h * 128 + dv];
    }
    *reinterpret_cast<uint4*>(Vt + (((size_t)bh * 256 + ks) * 128 + dv) * 8) = *reinterpret_cast<uint4*>(tmp);
  }
}

// ---------------- MFMA flash attention v8b (measured-good, unchanged) ----------------
__global__ __launch_bounds__(256, 2)
void flash_attn8(const u16* __restrict__ Q, const u16* __restrict__ Kc,
                 const u16* __restrict__ Vt, u16* __restrict__ O) {
  __shared__ __attribute__((aligned(16))) u16 Ks[2][24 * 64 * 8];  // 49 KB dbuf [kq][key][8]
  __shared__ __attribute__((aligned(16))) u16 Vs[8 * 128 * 8];     // 16 KB [kc][dv][8]
  __shared__ __attribute__((aligned(16))) u16 Ps[4 * 16 * 72];     // 9 KB per-wave P, stride 72

  const int blk = blockIdx.x;
  const int bh = ((blk & 7) << 2) | (blk >> 7);
  const int tpair = (blk >> 3) & 15;
  const int b = bh >> 4, h = bh & 15;
  const int tid = threadIdx.x, lane = tid & 63, wave = tid >> 6;
  const int quad = lane >> 4, l16 = lane & 15;
  u16* PsW = Ps + wave * 16 * 72;

  bf16x8 onesf;
  #pragma unroll
  for (int j = 0; j < 8; j++) onesf[j] = (l16 == 0) ? (__bf16)1.0f : (__bf16)0.0f;

  auto stageK = [&](u16* KsB, int kk) {
    #pragma unroll
    for (int ii = 0; ii < 6; ii++) {
      int kq = wave * 6 + ii;
      gld16(Kc + (((size_t)bh * 24 + kq) * 2048 + kk + lane) * 8, KsB + kq * 64 * 8);
    }
  };
  auto stageV = [&](int kk) {
    #pragma unroll
    for (int jj = 0; jj < 4; jj++) {
      int vc = wave * 4 + jj, kc = vc >> 1, dvh = vc & 1;
      gld16(Vt + (((size_t)bh * 256 + (kk >> 3) + kc) * 128 + dvh * 64 + lane) * 8,
            Vs + (kc * 128 + dvh * 64) * 8);
    }
  };

  for (int phase = 0; phase < 2; phase++) {
    const int qt = phase == 0 ? tpair : 31 - tpair;
    const int q0 = qt * 64;
    const int nk = (qt + 1) * 64;

    bf16x8 qf[6];
    {
      int qrow = q0 + wave * 16 + l16;
      const u16* qp = Q + ((size_t)bh * 2048 + qrow) * 192 + quad * 8;
      #pragma unroll
      for (int kc = 0; kc < 6; kc++)
        qf[kc] = *reinterpret_cast<const bf16x8*>(qp + kc * 32);
    }

    f32x4 zero = {0.f, 0.f, 0.f, 0.f};
    f32x4 oacc[9];
    #pragma unroll
    for (int nt = 0; nt < 9; nt++) oacc[nt] = zero;

    for (int k0 = 0; k0 < nk; k0 += 64) {
      const int cur = (k0 >> 6) & 1;
      const bool hasnext = (k0 + 64 < nk);

      __builtin_amdgcn_s_barrier();
      __builtin_amdgcn_sched_barrier(0);
      if (k0 == 0) stageK(Ks[0], 0);
      stageV(k0);
      if (hasnext) {
        stageK(Ks[cur ^ 1], k0 + 64);
        asm volatile("s_waitcnt vmcnt(10)" ::: "memory");
      } else {
        asm volatile("s_waitcnt vmcnt(4)" ::: "memory");
      }
      __builtin_amdgcn_sched_barrier(0);
      __builtin_amdgcn_s_barrier();
      __builtin_amdgcn_sched_barrier(0);

      const u16* KsC = Ks[cur];

      f32x4 sacc[4];
      #pragma unroll
      for (int nt = 0; nt < 4; nt++) sacc[nt] = zero;
      #pragma unroll
      for (int kc = 0; kc < 6; kc++) {
        #pragma unroll
        for (int nt = 0; nt < 4; nt++) {
          bf16x8 kb = *reinterpret_cast<const bf16x8*>(KsC + ((kc * 4 + quad) * 64 + nt * 16 + l16) * 8);
          sacc[nt] = __builtin_amdgcn_mfma_f32_16x16x32_bf16(qf[kc], kb, sacc[nt], 0, 0, 0);
        }
      }

      if (k0 + 63 <= q0 + wave * 16) {
        #pragma unroll
        for (int r = 0; r < 4; r++) {
          #pragma unroll
          for (int nt = 0; nt < 4; nt++) {
            float p = EXP2(sacc[nt][r]);
            PsW[(quad * 4 + r) * 72 + nt * 16 + l16] = f2b_hw(p);
          }
        }
      } else {
        #pragma unroll
        for (int r = 0; r < 4; r++) {
          int qrow_g = q0 + wave * 16 + quad * 4 + r;
          #pragma unroll
          for (int nt = 0; nt < 4; nt++) {
            int key = k0 + nt * 16 + l16;
            float e = EXP2(sacc[nt][r]);
            float p = (key <= qrow_g) ? e : 0.f;
            PsW[(quad * 4 + r) * 72 + nt * 16 + l16] = f2b_hw(p);
          }
        }
      }

      if (hasnext) asm volatile("s_waitcnt vmcnt(6)" ::: "memory");
      else         asm volatile("s_waitcnt vmcnt(0)" ::: "memory");
      __builtin_amdgcn_sched_barrier(0);
      __builtin_amdgcn_s_barrier();
      __builtin_amdgcn_sched_barrier(0);

      #pragma unroll
      for (int kcp = 0; kcp < 2; kcp++) {
        bf16x8 pa = *reinterpret_cast<const bf16x8*>(PsW + l16 * 72 + kcp * 32 + quad * 8);
        #pragma unroll
        for (int nt = 0; nt < 8; nt++) {
          bf16x8 vb = *reinterpret_cast<const bf16x8*>(Vs + ((kcp * 4 + quad) * 128 + nt * 16 + l16) * 8);
          oacc[nt] = __builtin_amdgcn_mfma_f32_16x16x32_bf16(pa, vb, oacc[nt], 0, 0, 0);
        }
        oacc[8] = __builtin_amdgcn_mfma_f32_16x16x32_bf16(pa, onesf, oacc[8], 0, 0, 0);
      }
    }

    #pragma unroll
    for (int r = 0; r < 4; r++) {
      float l = __shfl(oacc[8][r], lane & 48, 64);
      float inv = 1.0f / l;
      int s = q0 + wave * 16 + quad * 4 + r;
      #pragma unroll
      for (int nt = 0; nt < 8; nt++)
        O[((size_t)b * 2048 + s) * 2048 + h * 128 + nt * 16 + l16] = f2b(oacc[nt][r] * inv);
    }
  }
}

// ---------------- launch ----------------
extern "C" void kernel_launch(void* const* d_in, const int* in_sizes, int n_in,
                              void* d_out, int out_size, void* d_ws, size_t ws_size,
                              hipStream_t stream) {
  (void)in_sizes; (void)n_in; (void)out_size; (void)ws_size;
  const float* hs   = (const float*)d_in[0];
  const float* fc   = (const float*)d_in[2];
  const float* fs   = (const float*)d_in[3];
  const float* Wqd  = (const float*)d_in[4];
  const float* Wkvd = (const float*)d_in[5];
  const float* Wqu  = (const float*)d_in[6];
  const float* Wkvu = (const float*)d_in[7];
  const float* Wo   = (const float*)d_in[8];

  char* ws = (char*)d_ws;
  size_t off = 0;
  auto alloc = [&](size_t bytes) { size_t o = off; off += (bytes + 255) & ~(size_t)255; return o; };
  const size_t oHS   = alloc(16777216);  // hs_bf bf16 [4096][2048]
  const size_t oRA   = alloc(16777216);  // Vt bf16 [32][256][128][8]
  const size_t oRB   = alloc(25165824);  // q2 bf16 [4096][3072] -> Kc bf16
  const size_t oRC   = alloc(12582912);  // qlat bf16 [4096][1536]
  const size_t oRD   = alloc(25165824);  // Q bf16 [B*H][S][192]
  const size_t oRE   = alloc(34603008);  // t13 f32 [4096][2112] -> kvb bf16 [4096][4096] -> attn_out
  const size_t oKVL  = alloc(4194304);   // kvl bf16 [4096][512]
  const size_t oKR   = alloc(524288);    // krope bf16 [4096][64]
  const size_t oW13T  = alloc(8650752);  // [2112][2048] bf16
  const size_t oWquT  = alloc(9437184);
  const size_t oWkvuT = alloc(4194304);
  const size_t oWoT   = alloc(8388608);

  u16* hs_bf = (u16*)(ws + oHS);
  u16* Vt   = (u16*)(ws + oRA);
  u16* q2   = (u16*)(ws + oRB);
  u16* Kc   = (u16*)(ws + oRB);
  u16* qlat = (u16*)(ws + oRC);
  u16* Qb   = (u16*)(ws + oRD);
  float* t13 = (float*)(ws + oRE);
  u16* kvb  = (u16*)(ws + oRE);
  u16* attn_out = (u16*)(ws + oRE);
  u16* kvl  = (u16*)(ws + oKVL);
  u16* krope = (u16*)(ws + oKR);
  u16* W13T  = (u16*)(ws + oW13T);
  u16* WquT  = (u16*)(ws + oWquT);
  u16* WkvuT = (u16*)(ws + oWkvuT);
  u16* WoT   = (u16*)(ws + oWoT);

  cvt_f32_bf16<<<8192, 256, 0, stream>>>(hs, hs_bf, 2097152);
  transpose_all<<<14976, dim3(32, 8), 0, stream>>>(Wqd, Wkvd, Wqu, Wkvu, Wo, W13T, WquT, WkvuT, WoT);

  // fused down-projections: t13 = hs @ [Wq_down | Wkv_down]  (N=2112 ragged -> clamp+guard)
  gemm256<0><<<dim3(9, 16), 512, 0, stream>>>(hs_bf, W13T, t13, 2112, 2048);
  // fused rmsnorm(q-latent) + kv split
  norm_split<<<8192, 256, 0, stream>>>(t13, fc, fs, qlat, kvl, krope);
  // fused independent up-projections (concurrent): q2 and kvb
  gemm_up2<<<448, 512, 0, stream>>>(qlat, WquT, q2, kvl, WkvuT, kvb);
  // rope+pack Q (reads q2 BEFORE Kc overwrites the same buffer in assemble_kv2)
  rope_pack_q<<<4096, 256, 0, stream>>>(q2, fc, fs, Qb);
  assemble_kv2<<<dim3(256, 32), 256, 0, stream>>>(kvb, krope, Kc, Vt);
  // attention (v8b, measured)
  flash_attn8<<<dim3(512), 256, 0, stream>>>(Qb, Kc, Vt, attn_out);
  // output projection (fp32 out)
  gemm256<0><<<dim3(8, 16), 512, 0, stream>>>(attn_out, WoT, (float*)d_out, 2048, 2048);
}

// Round 13
// 412.929 us; speedup vs baseline: 1.2141x; 1.0706x over previous
//
#include <hip/hip_runtime.h>
#include <math.h>

// DeepSeekV3 MLA forward, MI355X gfx950.
// I/O fp32; internal math bf16 MFMA.
// GEMMs r12: gemm8 -- 256x128 tile, 8 waves (512 thr, 4Mx2N), BK=32, TRI-buffered
//            LDS (72 KB -> 2 blocks/CU: TLP kept, r12 lesson), stage-ahead-by-2,
//            counted vmcnt(3) boundary (never 0 mid-loop), one barrier/step,
//            setprio MFMA cluster. Grids 272/896/256 blocks: machine filled
//            (r12's 256^2 grids of 128-144 blocks left half the CUs idle).
// Flash v8b (measured): v7 K-dbuf counted-vmcnt + exp2 softmax + RTNE cast.
// Glue r8 (measured): transpose_all, norm_split, fused launches.
// B=2 S=2048 D=2048 H=16 NOPE=128 ROPE=64 DV=128 DQK=192 QLR=1536 KVLR=512

typedef unsigned short u16;
typedef __attribute__((ext_vector_type(8))) __bf16 bf16x8;
typedef __attribute__((ext_vector_type(4))) float f32x4;

#define DEV static __device__ __forceinline__

#if __has_builtin(__builtin_amdgcn_exp2f)
#define EXP2(x) __builtin_amdgcn_exp2f(x)
#else
#define EXP2(x) exp2f(x)
#endif

DEV float b2f(u16 v) { return __uint_as_float(((unsigned int)v) << 16); }
DEV u16 f2b(float f) {
  unsigned int u = __float_as_uint(f);
  u += 0x7fffu + ((u >> 16) & 1u);   // round-to-nearest-even
  return (u16)(u >> 16);
}
// native RTNE cvt -- compiler-generated, 1 instr, hazard-safe
DEV u16 f2b_hw(float f) {
  __bf16 h = (__bf16)f;
  u16 r;
  __builtin_memcpy(&r, &h, 2);
  return r;
}

DEV float waveReduceSum(float v) {
  #pragma unroll
  for (int o = 32; o > 0; o >>= 1) v += __shfl_down(v, o, 64);
  return v;
}

// async global->LDS, 16B per lane; LDS dest = wave-uniform base + lane*16
DEV void gld16(const u16* g, u16* l) {
  __builtin_amdgcn_global_load_lds((const __attribute__((address_space(1))) void*)g,
                                   (__attribute__((address_space(3))) void*)l, 16, 0, 0);
}

// ---------------- convert fp32 -> bf16 (flat) ----------------
__global__ __launch_bounds__(256)
void cvt_f32_bf16(const float* __restrict__ in, u16* __restrict__ out, int n4) {
  int i = blockIdx.x * 256 + threadIdx.x;
  if (i < n4) {
    float4 v = reinterpret_cast<const float4*>(in)[i];
    ushort4 o;
    o.x = f2b(v.x); o.y = f2b(v.y); o.z = f2b(v.z); o.w = f2b(v.w);
    reinterpret_cast<ushort4*>(out)[i] = o;
  }
}

// ---------------- fused transpose+convert of all 5 weights ----------------
__global__ __launch_bounds__(256)
void transpose_all(const float* __restrict__ Wqd, const float* __restrict__ Wkvd,
                   const float* __restrict__ Wqu, const float* __restrict__ Wkvu,
                   const float* __restrict__ Wo,
                   u16* __restrict__ W13T, u16* __restrict__ WquT,
                   u16* __restrict__ WkvuT, u16* __restrict__ WoT) {
  __shared__ u16 tile[32][33];
  int n = blockIdx.x;
  const float* in; u16* out; int R, C, gx, local;
  if (n < 3072)       { in = Wqd;  out = W13T;                        R = 2048; C = 1536; gx = 48;  local = n; }
  else if (n < 4224)  { in = Wkvd; out = W13T + (size_t)1536 * 2048;  R = 2048; C = 576;  gx = 18;  local = n - 3072; }
  else if (n < 8832)  { in = Wqu;  out = WquT;                        R = 1536; C = 3072; gx = 96;  local = n - 4224; }
  else if (n < 10880) { in = Wkvu; out = WkvuT;                       R = 512;  C = 4096; gx = 128; local = n - 8832; }
  else                { in = Wo;   out = WoT;                         R = 2048; C = 2048; gx = 64;  local = n - 10880; }
  int c0 = (local % gx) * 32, r0 = (local / gx) * 32;
  for (int i = threadIdx.y; i < 32; i += 8)
    tile[i][threadIdx.x] = f2b(in[(size_t)(r0 + i) * C + c0 + threadIdx.x]);
  __syncthreads();
  for (int i = threadIdx.y; i < 32; i += 8)
    out[(size_t)(c0 + i) * R + r0 + threadIdx.x] = tile[threadIdx.x][i];
}

// ---------------- gemm8 body: C[.][N] = A[.][K] * BT[N][K]^T ----------------
// 256x128 tile, 8 waves (4M x 2N), per-wave 64x64 output (4x4 frags, 64 acc VGPR).
// BK=32; TRI-buffered LDS (A 16KB + B 8KB per buf = 72KB total -> 2 blocks/CU).
// Pipeline: prologue stage(0),stage(1); step t: vmcnt(3) [retire t's 3 loads,
// keep t+1's flying] -> barrier -> read 8 frags, issue stage(t+2) (3 loads),
// setprio(1) 16 MFMA setprio(0). Loads issued ~2 K-steps before their wait;
// vmcnt never 0 mid-loop (T4). Tri-buffer makes the single barrier safe: step
// t+1's staging targets buf[(t+3)%3] == buf[t%3] only after the t+1 barrier
// joins all waves' reads of buf[t%3].
// LDS unit map (16B units): u = row*4 + (kq ^ ((row>>1)&3)) -- 64B-coalesced
// staging sources, 2-way (free) read aliasing, 0 bank conflicts (measured).
template<int OUT_BF16>
DEV void gemm8_body(const u16* __restrict__ A, const u16* __restrict__ BT, void* __restrict__ Cp,
                    int N, int K, int gx, int nwg, int orig,
                    u16 (*As)[8192], u16 (*Bs)[4096]) {
  const int tid = threadIdx.x;           // 0..511
  const int lane = tid & 63;
  const int wave = tid >> 6;             // 0..7
  const int wm = (wave >> 1) * 64;       // 0/64/128/192
  const int wn = (wave & 1) * 64;        // 0/64
  const int q = lane >> 4;
  const int l16 = lane & 15;

  // bijective XCD-chunk swizzle (nwg % 8 == 0 at every call site)
  const int cpx = nwg >> 3;
  const int swz = (orig & 7) * cpx + (orig >> 3);
  const int bm = (swz / gx) * 256;
  const int bn = (swz % gx) * 128;

  auto stageA = [&](int buf, int k0) {   // 256x32 tile: 1024 units, 2 loads/lane
    #pragma unroll
    for (int i = 0; i < 2; i++) {
      int ub = i * 512 + wave * 64;      // wave-uniform chunk base (16B units)
      int u = ub + lane;
      int row = u >> 2;
      int kq = (u & 3) ^ ((u >> 3) & 3);
      gld16(A + (size_t)(bm + row) * K + k0 + kq * 8, As[buf] + ub * 8);
    }
  };
  auto stageB = [&](int buf, int k0) {   // 128x32 tile: 512 units, 1 load/lane
    int ub = wave * 64;
    int u = ub + lane;
    int row = u >> 2;
    int kq = (u & 3) ^ ((u >> 3) & 3);
    int rB = bn + row;
    if (rB >= N) rB = N - 1;             // clamp: finite garbage, cols >= N never stored
    gld16(BT + (size_t)rB * K + k0 + kq * 8, Bs[buf] + ub * 8);
  };

  f32x4 zero = {0.f, 0.f, 0.f, 0.f};
  f32x4 acc[4][4];
  #pragma unroll
  for (int i = 0; i < 4; i++)
    #pragma unroll
    for (int j = 0; j < 4; j++) acc[i][j] = zero;

  const int nt = K >> 5;
  stageA(0, 0);  stageB(0, 0);           // 3 loads
  stageA(1, 32); stageB(1, 32);          // 3 loads -> 6 outstanding

  for (int t = 0; t < nt; ++t) {
    const int cur = t % 3;
    if (t + 1 < nt) asm volatile("s_waitcnt vmcnt(3)" ::: "memory");
    else            asm volatile("s_waitcnt vmcnt(0)" ::: "memory");
    __builtin_amdgcn_sched_barrier(0);
    __builtin_amdgcn_s_barrier();        // publish buf[cur]; orders reads vs future stages
    __builtin_amdgcn_sched_barrier(0);

    const u16* Ab = As[cur];
    const u16* Bb = Bs[cur];
    const int nxt = (t + 2) % 3;
    const bool pre = (t + 2) < nt;
    const int kpre = (t + 2) * 32;

    bf16x8 af[4], bfr[4];
    #pragma unroll
    for (int j = 0; j < 4; j++) {
      int rowA = wm + j * 16 + l16;
      af[j]  = *reinterpret_cast<const bf16x8*>(Ab + (((rowA) << 2) | (q ^ ((rowA >> 1) & 3))) * 8);
      int rowB = wn + j * 16 + l16;
      bfr[j] = *reinterpret_cast<const bf16x8*>(Bb + (((rowB) << 2) | (q ^ ((rowB >> 1) & 3))) * 8);
    }
    if (pre) { stageA(nxt, kpre); stageB(nxt, kpre); }
    __builtin_amdgcn_s_setprio(1);
    #pragma unroll
    for (int mt = 0; mt < 4; mt++)
      #pragma unroll
      for (int j = 0; j < 4; j++)
        acc[mt][j] = __builtin_amdgcn_mfma_f32_16x16x32_bf16(af[mt], bfr[j], acc[mt][j], 0, 0, 0);
    __builtin_amdgcn_s_setprio(0);
  }

  float* Cf = (float*)Cp;
  u16* Cb = (u16*)Cp;
  #pragma unroll
  for (int mt = 0; mt < 4; mt++) {
    #pragma unroll
    for (int j = 0; j < 4; j++) {
      int col = bn + wn + j * 16 + l16;
      if (col < N) {
        int row0 = bm + wm + mt * 16 + q * 4;
        #pragma unroll
        for (int r = 0; r < 4; r++) {
          size_t idx = (size_t)(row0 + r) * N + col;
          float v = acc[mt][j][r];
          if (OUT_BF16) Cb[idx] = f2b(v); else Cf[idx] = v;
        }
      }
    }
  }
}

template<int OUT_BF16>
__global__ __launch_bounds__(512, 4)
void gemm8(const u16* __restrict__ A, const u16* __restrict__ BT, void* __restrict__ Cp,
           int N, int K) {
  __shared__ __attribute__((aligned(16))) u16 As[3][8192];
  __shared__ __attribute__((aligned(16))) u16 Bs[3][4096];
  const int gx = gridDim.x;
  const int nwg = gx * gridDim.y;
  const int orig = blockIdx.y * gx + blockIdx.x;
  gemm8_body<OUT_BF16>(A, BT, Cp, N, K, gx, nwg, orig, As, Bs);
}

// fused independent up-projections: blocks 0..383 = q-up (4096x3072 K=1536, gx=24),
// 384..895 = kv-up (4096x4096 K=512, gx=32). Long jobs first (LPT). Both %8==0.
__global__ __launch_bounds__(512, 4)
void gemm_up2(const u16* __restrict__ qlat, const u16* __restrict__ WquT, u16* __restrict__ q2,
              const u16* __restrict__ kvl, const u16* __restrict__ WkvuT, u16* __restrict__ kvb) {
  __shared__ __attribute__((aligned(16))) u16 As[3][8192];
  __shared__ __attribute__((aligned(16))) u16 Bs[3][4096];
  int n = blockIdx.x;
  if (n < 384) gemm8_body<1>(qlat, WquT, q2, 3072, 1536, 24, 384, n, As, Bs);
  else         gemm8_body<1>(kvl, WkvuT, kvb, 4096, 512, 32, 512, n - 384, As, Bs);
}

// ---------------- fused norm/split: blocks 0..4095 rmsnorm(q-latent), 4096..8191 kv-split ----------------
__global__ __launch_bounds__(256)
void norm_split(const float* __restrict__ t13, const float* __restrict__ fc, const float* __restrict__ fs,
                u16* __restrict__ qlat, u16* __restrict__ kvl, u16* __restrict__ krope) {
  __shared__ float red[4];
  __shared__ float s_scale;
  int lane = threadIdx.x & 63, wid = threadIdx.x >> 6;
  if (blockIdx.x < 4096) {
    int row = blockIdx.x;
    const float* x = t13 + (size_t)row * 2112;
    float ss = 0.f;
    for (int i = threadIdx.x; i < 1536; i += 256) { float v = x[i]; ss += v * v; }
    ss = waveReduceSum(ss);
    if (lane == 0) red[wid] = ss;
    __syncthreads();
    if (threadIdx.x == 0)
      s_scale = rsqrtf((red[0] + red[1] + red[2] + red[3]) * (1.0f / 1536.0f) + 1e-5f);
    __syncthreads();
    float sc = s_scale;
    u16* o = qlat + (size_t)row * 1536;
    for (int i = threadIdx.x; i < 1536; i += 256) o[i] = f2b(x[i] * sc);
  } else {
    int row = blockIdx.x - 4096;
    int s = row & 2047;
    const float* x = t13 + (size_t)row * 2112 + 1536;
    float ss = 0.f;
    for (int i = threadIdx.x; i < 512; i += 256) { float v = x[i]; ss += v * v; }
    ss = waveReduceSum(ss);
    if (lane == 0) red[wid] = ss;
    __syncthreads();
    if (threadIdx.x == 0)
      s_scale = rsqrtf((red[0] + red[1] + red[2] + red[3]) * (1.0f / 512.0f) + 1e-5f);
    __syncthreads();
    float sc = s_scale;
    for (int i = threadIdx.x; i < 512; i += 256) kvl[(size_t)row * 512 + i] = f2b(x[i] * sc);
    if (threadIdx.x < 32) {
      int i = threadIdx.x;
      float cc = fc[s * 32 + i], sn = fs[s * 32 + i];
      float x0 = x[512 + 2 * i], x1 = x[512 + 2 * i + 1];
      krope[(size_t)row * 64 + 2 * i]     = f2b(x0 * cc - x1 * sn);
      krope[(size_t)row * 64 + 2 * i + 1] = f2b(x0 * sn + x1 * cc);
    }
  }
}

// ---------------- rope + pack Q, PRESCALED by log2e/sqrt(192) ----------------
__global__ __launch_bounds__(256)
void rope_pack_q(const u16* __restrict__ q2, const float* __restrict__ fc, const float* __restrict__ fs,
                 u16* __restrict__ Q) {
  const float scale = 0.10411756711f;  // (1/sqrt(192)) * log2(e)
  int bs = blockIdx.x;
  int b = bs >> 11, s = bs & 2047;
  __shared__ float c[32], sn[32];
  if (threadIdx.x < 32) {
    c[threadIdx.x] = fc[s * 32 + threadIdx.x];
    sn[threadIdx.x] = fs[s * 32 + threadIdx.x];
  }
  __syncthreads();
  const u16* qrow = q2 + (size_t)bs * 3072;
  for (int t = threadIdx.x; t < 512; t += 256) {
    int h = t >> 5, i = t & 31;
    float x0 = b2f(qrow[h * 192 + 128 + 2 * i]);
    float x1 = b2f(qrow[h * 192 + 128 + 2 * i + 1]);
    size_t base = ((size_t)(b * 16 + h) * 2048 + s) * 192;
    Q[base + 2 * i]     = f2b((x0 * c[i] - x1 * sn[i]) * scale);
    Q[base + 2 * i + 1] = f2b((x0 * sn[i] + x1 * c[i]) * scale);
  }
  for (int t = threadIdx.x; t < 2048; t += 256) {
    int h = t >> 7, j = t & 127;
    Q[((size_t)(b * 16 + h) * 2048 + s) * 192 + 64 + j] = f2b(b2f(qrow[h * 192 + j]) * scale);
  }
}

// ---------------- assemble K chunked + V transposed chunked ----------------
__global__ __launch_bounds__(256)
void assemble_kv2(const u16* __restrict__ kvb, const u16* __restrict__ krope,
                  u16* __restrict__ Kc, u16* __restrict__ Vt) {
  int ks = blockIdx.x;   // 0..255
  int bh = blockIdx.y;   // 0..31
  int b = bh >> 4, h = bh & 15;
  int t = threadIdx.x;
  if (t < 192) {
    int kq = t >> 3, sl = t & 7;
    int s = ks * 8 + sl;
    size_t bs = (size_t)(b * 2048 + s);
    uint4 v;
    if (kq < 8) v = *reinterpret_cast<const uint4*>(krope + bs * 64 + kq * 8);
    else        v = *reinterpret_cast<const uint4*>(kvb + bs * 4096 + h * 128 + (kq - 8) * 8);
    *reinterpret_cast<uint4*>(Kc + (((size_t)bh * 24 + kq) * 2048 + s) * 8) = v;
  }
  if (t < 128) {
    int dv = t;
    u16 tmp[8];
    #pragma unroll
    for (int j = 0; j < 8; j++) {
      int s = ks * 8 + j;
      tmp[j] = kvb[(size_t)(b * 2048 + s) * 4096 + 2048 + h * 128 + dv];
    }
    *reinterpret_cast<uint4*>(Vt + (((size_t)bh * 256 + ks) * 128 + dv) * 8) = *reinterpret_cast<uint4*>(tmp);
  }
}

// ---------------- MFMA flash attention v8b (measured-good, unchanged) ----------------
__global__ __launch_bounds__(256, 2)
void flash_attn8(const u16* __restrict__ Q, const u16* __restrict__ Kc,
                 const u16* __restrict__ Vt, u16* __restrict__ O) {
  __shared__ __attribute__((aligned(16))) u16 Ks[2][24 * 64 * 8];  // 49 KB dbuf [kq][key][8]
  __shared__ __attribute__((aligned(16))) u16 Vs[8 * 128 * 8];     // 16 KB [kc][dv][8]
  __shared__ __attribute__((aligned(16))) u16 Ps[4 * 16 * 72];     // 9 KB per-wave P, stride 72

  const int blk = blockIdx.x;
  const int bh = ((blk & 7) << 2) | (blk >> 7);
  const int tpair = (blk >> 3) & 15;
  const int b = bh >> 4, h = bh & 15;
  const int tid = threadIdx.x, lane = tid & 63, wave = tid >> 6;
  const int quad = lane >> 4, l16 = lane & 15;
  u16* PsW = Ps + wave * 16 * 72;

  bf16x8 onesf;
  #pragma unroll
  for (int j = 0; j < 8; j++) onesf[j] = (l16 == 0) ? (__bf16)1.0f : (__bf16)0.0f;

  auto stageK = [&](u16* KsB, int kk) {
    #pragma unroll
    for (int ii = 0; ii < 6; ii++) {
      int kq = wave * 6 + ii;
      gld16(Kc + (((size_t)bh * 24 + kq) * 2048 + kk + lane) * 8, KsB + kq * 64 * 8);
    }
  };
  auto stageV = [&](int kk) {
    #pragma unroll
    for (int jj = 0; jj < 4; jj++) {
      int vc = wave * 4 + jj, kc = vc >> 1, dvh = vc & 1;
      gld16(Vt + (((size_t)bh * 256 + (kk >> 3) + kc) * 128 + dvh * 64 + lane) * 8,
            Vs + (kc * 128 + dvh * 64) * 8);
    }
  };

  for (int phase = 0; phase < 2; phase++) {
    const int qt = phase == 0 ? tpair : 31 - tpair;
    const int q0 = qt * 64;
    const int nk = (qt + 1) * 64;

    bf16x8 qf[6];
    {
      int qrow = q0 + wave * 16 + l16;
      const u16* qp = Q + ((size_t)bh * 2048 + qrow) * 192 + quad * 8;
      #pragma unroll
      for (int kc = 0; kc < 6; kc++)
        qf[kc] = *reinterpret_cast<const bf16x8*>(qp + kc * 32);
    }

    f32x4 zero = {0.f, 0.f, 0.f, 0.f};
    f32x4 oacc[9];
    #pragma unroll
    for (int nt = 0; nt < 9; nt++) oacc[nt] = zero;

    for (int k0 = 0; k0 < nk; k0 += 64) {
      const int cur = (k0 >> 6) & 1;
      const bool hasnext = (k0 + 64 < nk);

      __builtin_amdgcn_s_barrier();
      __builtin_amdgcn_sched_barrier(0);
      if (k0 == 0) stageK(Ks[0], 0);
      stageV(k0);
      if (hasnext) {
        stageK(Ks[cur ^ 1], k0 + 64);
        asm volatile("s_waitcnt vmcnt(10)" ::: "memory");
      } else {
        asm volatile("s_waitcnt vmcnt(4)" ::: "memory");
      }
      __builtin_amdgcn_sched_barrier(0);
      __builtin_amdgcn_s_barrier();
      __builtin_amdgcn_sched_barrier(0);

      const u16* KsC = Ks[cur];

      f32x4 sacc[4];
      #pragma unroll
      for (int nt = 0; nt < 4; nt++) sacc[nt] = zero;
      #pragma unroll
      for (int kc = 0; kc < 6; kc++) {
        #pragma unroll
        for (int nt = 0; nt < 4; nt++) {
          bf16x8 kb = *reinterpret_cast<const bf16x8*>(KsC + ((kc * 4 + quad) * 64 + nt * 16 + l16) * 8);
          sacc[nt] = __builtin_amdgcn_mfma_f32_16x16x32_bf16(qf[kc], kb, sacc[nt], 0, 0, 0);
        }
      }

      if (k0 + 63 <= q0 + wave * 16) {
        #pragma unroll
        for (int r = 0; r < 4; r++) {
          #pragma unroll
          for (int nt = 0; nt < 4; nt++) {
            float p = EXP2(sacc[nt][r]);
            PsW[(quad * 4 + r) * 72 + nt * 16 + l16] = f2b_hw(p);
          }
        }
      } else {
        #pragma unroll
        for (int r = 0; r < 4; r++) {
          int qrow_g = q0 + wave * 16 + quad * 4 + r;
          #pragma unroll
          for (int nt = 0; nt < 4; nt++) {
            int key = k0 + nt * 16 + l16;
            float e = EXP2(sacc[nt][r]);
            float p = (key <= qrow_g) ? e : 0.f;
            PsW[(quad * 4 + r) * 72 + nt * 16 + l16] = f2b_hw(p);
          }
        }
      }

      if (hasnext) asm volatile("s_waitcnt vmcnt(6)" ::: "memory");
      else         asm volatile("s_waitcnt vmcnt(0)" ::: "memory");
      __builtin_amdgcn_sched_barrier(0);
      __builtin_amdgcn_s_barrier();
      __builtin_amdgcn_sched_barrier(0);

      #pragma unroll
      for (int kcp = 0; kcp < 2; kcp++) {
        bf16x8 pa = *reinterpret_cast<const bf16x8*>(PsW + l16 * 72 + kcp * 32 + quad * 8);
        #pragma unroll
        for (int nt = 0; nt < 8; nt++) {
          bf16x8 vb = *reinterpret_cast<const bf16x8*>(Vs + ((kcp * 4 + quad) * 128 + nt * 16 + l16) * 8);
          oacc[nt] = __builtin_amdgcn_mfma_f32_16x16x32_bf16(pa, vb, oacc[nt], 0, 0, 0);
        }
        oacc[8] = __builtin_amdgcn_mfma_f32_16x16x32_bf16(pa, onesf, oacc[8], 0, 0, 0);
      }
    }

    #pragma unroll
    for (int r = 0; r < 4; r++) {
      float l = __shfl(oacc[8][r], lane & 48, 64);
      float inv = 1.0f / l;
      int s = q0 + wave * 16 + quad * 4 + r;
      #pragma unroll
      for (int nt = 0; nt < 8; nt++)
        O[((size_t)b * 2048 + s) * 2048 + h * 128 + nt * 16 + l16] = f2b(oacc[nt][r] * inv);
    }
  }
}

// ---------------- launch ----------------
extern "C" void kernel_launch(void* const* d_in, const int* in_sizes, int n_in,
                              void* d_out, int out_size, void* d_ws, size_t ws_size,
                              hipStream_t stream) {
  (void)in_sizes; (void)n_in; (void)out_size; (void)ws_size;
  const float* hs   = (const float*)d_in[0];
  const float* fc   = (const float*)d_in[2];
  const float* fs   = (const float*)d_in[3];
  const float* Wqd  = (const float*)d_in[4];
  const float* Wkvd = (const float*)d_in[5];
  const float* Wqu  = (const float*)d_in[6];
  const float* Wkvu = (const float*)d_in[7];
  const float* Wo   = (const float*)d_in[8];

  char* ws = (char*)d_ws;
  size_t off = 0;
  auto alloc = [&](size_t bytes) { size_t o = off; off += (bytes + 255) & ~(size_t)255; return o; };
  const size_t oHS   = alloc(16777216);  // hs_bf bf16 [4096][2048]
  const size_t oRA   = alloc(16777216);  // Vt bf16 [32][256][128][8]
  const size_t oRB   = alloc(25165824);  // q2 bf16 [4096][3072] -> Kc bf16
  const size_t oRC   = alloc(12582912);  // qlat bf16 [4096][1536]
  const size_t oRD   = alloc(25165824);  // Q bf16 [B*H][S][192]
  const size_t oRE   = alloc(34603008);  // t13 f32 [4096][2112] -> kvb bf16 [4096][4096] -> attn_out
  const size_t oKVL  = alloc(4194304);   // kvl bf16 [4096][512]
  const size_t oKR   = alloc(524288);    // krope bf16 [4096][64]
  const size_t oW13T  = alloc(8650752);  // [2112][2048] bf16
  const size_t oWquT  = alloc(9437184);
  const size_t oWkvuT = alloc(4194304);
  const size_t oWoT   = alloc(8388608);

  u16* hs_bf = (u16*)(ws + oHS);
  u16* Vt   = (u16*)(ws + oRA);
  u16* q2   = (u16*)(ws + oRB);
  u16* Kc   = (u16*)(ws + oRB);
  u16* qlat = (u16*)(ws + oRC);
  u16* Qb   = (u16*)(ws + oRD);
  float* t13 = (float*)(ws + oRE);
  u16* kvb  = (u16*)(ws + oRE);
  u16* attn_out = (u16*)(ws + oRE);
  u16* kvl  = (u16*)(ws + oKVL);
  u16* krope = (u16*)(ws + oKR);
  u16* W13T  = (u16*)(ws + oW13T);
  u16* WquT  = (u16*)(ws + oWquT);
  u16* WkvuT = (u16*)(ws + oWkvuT);
  u16* WoT   = (u16*)(ws + oWoT);

  cvt_f32_bf16<<<8192, 256, 0, stream>>>(hs, hs_bf, 2097152);
  transpose_all<<<14976, dim3(32, 8), 0, stream>>>(Wqd, Wkvd, Wqu, Wkvu, Wo, W13T, WquT, WkvuT, WoT);

  // fused down-projections: t13 = hs @ [Wq_down | Wkv_down]  (N=2112 ragged -> clamp+guard)
  gemm8<0><<<dim3(17, 16), 512, 0, stream>>>(hs_bf, W13T, t13, 2112, 2048);
  // fused rmsnorm(q-latent) + kv split
  norm_split<<<8192, 256, 0, stream>>>(t13, fc, fs, qlat, kvl, krope);
  // fused independent up-projections (concurrent): q2 and kvb
  gemm_up2<<<896, 512, 0, stream>>>(qlat, WquT, q2, kvl, WkvuT, kvb);
  // rope+pack Q (reads q2 BEFORE Kc overwrites the same buffer in assemble_kv2)
  rope_pack_q<<<4096, 256, 0, stream>>>(q2, fc, fs, Qb);
  assemble_kv2<<<dim3(256, 32), 256, 0, stream>>>(kvb, krope, Kc, Vt);
  // attention (v8b, measured)
  flash_attn8<<<dim3(512), 256, 0, stream>>>(Qb, Kc, Vt, attn_out);
  // output projection (fp32 out)
  gemm8<0><<<dim3(16, 16), 512, 0, stream>>>(attn_out, WoT, (float*)d_out, 2048, 2048);
}

// Round 14
// 409.022 us; speedup vs baseline: 1.2256x; 1.0096x over previous
//
#include <hip/hip_runtime.h>
#include <math.h>

// DeepSeekV3 MLA forward, MI355X gfx950.
// I/O fp32; internal math bf16 MFMA.
// Flash v9: JOINT balanced-pair processing. Pair {t,31-t} shares one key loop:
//           each staged K/V tile serves 32 q/wave (2x16 sub-tiles A=small,B=big)
//           -> LDS read per unit work ~1.6x lower (the measured 26% MfmaUtil cap),
//           staging steps 33 -> 32-t (avg -26%). v8's counted vmcnt(10)/(6)
//           3-barrier scheme and LDS 74.75KB (2 blocks/CU) kept verbatim.
//           Per-block MFMA work uniform: 84(t+1)+42(31-2t) = 1386 for all t.
// GEMMs r12 (measured 413): gemm8 256x128, tri-buffer, stage-ahead-2, vmcnt(3).
// Glue r8 (measured): transpose_all, norm_split, fused launches.
// B=2 S=2048 D=2048 H=16 NOPE=128 ROPE=64 DV=128 DQK=192 QLR=1536 KVLR=512

typedef unsigned short u16;
typedef __attribute__((ext_vector_type(8))) __bf16 bf16x8;
typedef __attribute__((ext_vector_type(4))) float f32x4;

#define DEV static __device__ __forceinline__

#if __has_builtin(__builtin_amdgcn_exp2f)
#define EXP2(x) __builtin_amdgcn_exp2f(x)
#else
#define EXP2(x) exp2f(x)
#endif

DEV float b2f(u16 v) { return __uint_as_float(((unsigned int)v) << 16); }
DEV u16 f2b(float f) {
  unsigned int u = __float_as_uint(f);
  u += 0x7fffu + ((u >> 16) & 1u);   // round-to-nearest-even
  return (u16)(u >> 16);
}
// native RTNE cvt -- compiler-generated, 1 instr, hazard-safe
DEV u16 f2b_hw(float f) {
  __bf16 h = (__bf16)f;
  u16 r;
  __builtin_memcpy(&r, &h, 2);
  return r;
}

DEV float waveReduceSum(float v) {
  #pragma unroll
  for (int o = 32; o > 0; o >>= 1) v += __shfl_down(v, o, 64);
  return v;
}

// async global->LDS, 16B per lane; LDS dest = wave-uniform base + lane*16
DEV void gld16(const u16* g, u16* l) {
  __builtin_amdgcn_global_load_lds((const __attribute__((address_space(1))) void*)g,
                                   (__attribute__((address_space(3))) void*)l, 16, 0, 0);
}

// ---------------- convert fp32 -> bf16 (flat) ----------------
__global__ __launch_bounds__(256)
void cvt_f32_bf16(const float* __restrict__ in, u16* __restrict__ out, int n4) {
  int i = blockIdx.x * 256 + threadIdx.x;
  if (i < n4) {
    float4 v = reinterpret_cast<const float4*>(in)[i];
    ushort4 o;
    o.x = f2b(v.x); o.y = f2b(v.y); o.z = f2b(v.z); o.w = f2b(v.w);
    reinterpret_cast<ushort4*>(out)[i] = o;
  }
}

// ---------------- fused transpose+convert of all 5 weights ----------------
__global__ __launch_bounds__(256)
void transpose_all(const float* __restrict__ Wqd, const float* __restrict__ Wkvd,
                   const float* __restrict__ Wqu, const float* __restrict__ Wkvu,
                   const float* __restrict__ Wo,
                   u16* __restrict__ W13T, u16* __restrict__ WquT,
                   u16* __restrict__ WkvuT, u16* __restrict__ WoT) {
  __shared__ u16 tile[32][33];
  int n = blockIdx.x;
  const float* in; u16* out; int R, C, gx, local;
  if (n < 3072)       { in = Wqd;  out = W13T;                        R = 2048; C = 1536; gx = 48;  local = n; }
  else if (n < 4224)  { in = Wkvd; out = W13T + (size_t)1536 * 2048;  R = 2048; C = 576;  gx = 18;  local = n - 3072; }
  else if (n < 8832)  { in = Wqu;  out = WquT;                        R = 1536; C = 3072; gx = 96;  local = n - 4224; }
  else if (n < 10880) { in = Wkvu; out = WkvuT;                       R = 512;  C = 4096; gx = 128; local = n - 8832; }
  else                { in = Wo;   out = WoT;                         R = 2048; C = 2048; gx = 64;  local = n - 10880; }
  int c0 = (local % gx) * 32, r0 = (local / gx) * 32;
  for (int i = threadIdx.y; i < 32; i += 8)
    tile[i][threadIdx.x] = f2b(in[(size_t)(r0 + i) * C + c0 + threadIdx.x]);
  __syncthreads();
  for (int i = threadIdx.y; i < 32; i += 8)
    out[(size_t)(c0 + i) * R + r0 + threadIdx.x] = tile[threadIdx.x][i];
}

// ---------------- gemm8 body: C[.][N] = A[.][K] * BT[N][K]^T (r12, measured) ----------------
template<int OUT_BF16>
DEV void gemm8_body(const u16* __restrict__ A, const u16* __restrict__ BT, void* __restrict__ Cp,
                    int N, int K, int gx, int nwg, int orig,
                    u16 (*As)[8192], u16 (*Bs)[4096]) {
  const int tid = threadIdx.x;           // 0..511
  const int lane = tid & 63;
  const int wave = tid >> 6;             // 0..7
  const int wm = (wave >> 1) * 64;       // 0/64/128/192
  const int wn = (wave & 1) * 64;        // 0/64
  const int q = lane >> 4;
  const int l16 = lane & 15;

  const int cpx = nwg >> 3;
  const int swz = (orig & 7) * cpx + (orig >> 3);
  const int bm = (swz / gx) * 256;
  const int bn = (swz % gx) * 128;

  auto stageA = [&](int buf, int k0) {
    #pragma unroll
    for (int i = 0; i < 2; i++) {
      int ub = i * 512 + wave * 64;
      int u = ub + lane;
      int row = u >> 2;
      int kq = (u & 3) ^ ((u >> 3) & 3);
      gld16(A + (size_t)(bm + row) * K + k0 + kq * 8, As[buf] + ub * 8);
    }
  };
  auto stageB = [&](int buf, int k0) {
    int ub = wave * 64;
    int u = ub + lane;
    int row = u >> 2;
    int kq = (u & 3) ^ ((u >> 3) & 3);
    int rB = bn + row;
    if (rB >= N) rB = N - 1;
    gld16(BT + (size_t)rB * K + k0 + kq * 8, Bs[buf] + ub * 8);
  };

  f32x4 zero = {0.f, 0.f, 0.f, 0.f};
  f32x4 acc[4][4];
  #pragma unroll
  for (int i = 0; i < 4; i++)
    #pragma unroll
    for (int j = 0; j < 4; j++) acc[i][j] = zero;

  const int nt = K >> 5;
  stageA(0, 0);  stageB(0, 0);
  stageA(1, 32); stageB(1, 32);

  for (int t = 0; t < nt; ++t) {
    const int cur = t % 3;
    if (t + 1 < nt) asm volatile("s_waitcnt vmcnt(3)" ::: "memory");
    else            asm volatile("s_waitcnt vmcnt(0)" ::: "memory");
    __builtin_amdgcn_sched_barrier(0);
    __builtin_amdgcn_s_barrier();
    __builtin_amdgcn_sched_barrier(0);

    const u16* Ab = As[cur];
    const u16* Bb = Bs[cur];
    const int nxt = (t + 2) % 3;
    const bool pre = (t + 2) < nt;
    const int kpre = (t + 2) * 32;

    bf16x8 af[4], bfr[4];
    #pragma unroll
    for (int j = 0; j < 4; j++) {
      int rowA = wm + j * 16 + l16;
      af[j]  = *reinterpret_cast<const bf16x8*>(Ab + (((rowA) << 2) | (q ^ ((rowA >> 1) & 3))) * 8);
      int rowB = wn + j * 16 + l16;
      bfr[j] = *reinterpret_cast<const bf16x8*>(Bb + (((rowB) << 2) | (q ^ ((rowB >> 1) & 3))) * 8);
    }
    if (pre) { stageA(nxt, kpre); stageB(nxt, kpre); }
    __builtin_amdgcn_s_setprio(1);
    #pragma unroll
    for (int mt = 0; mt < 4; mt++)
      #pragma unroll
      for (int j = 0; j < 4; j++)
        acc[mt][j] = __builtin_amdgcn_mfma_f32_16x16x32_bf16(af[mt], bfr[j], acc[mt][j], 0, 0, 0);
    __builtin_amdgcn_s_setprio(0);
  }

  float* Cf = (float*)Cp;
  u16* Cb = (u16*)Cp;
  #pragma unroll
  for (int mt = 0; mt < 4; mt++) {
    #pragma unroll
    for (int j = 0; j < 4; j++) {
      int col = bn + wn + j * 16 + l16;
      if (col < N) {
        int row0 = bm + wm + mt * 16 + q * 4;
        #pragma unroll
        for (int r = 0; r < 4; r++) {
          size_t idx = (size_t)(row0 + r) * N + col;
          float v = acc[mt][j][r];
          if (OUT_BF16) Cb[idx] = f2b(v); else Cf[idx] = v;
        }
      }
    }
  }
}

template<int OUT_BF16>
__global__ __launch_bounds__(512, 4)
void gemm8(const u16* __restrict__ A, const u16* __restrict__ BT, void* __restrict__ Cp,
           int N, int K) {
  __shared__ __attribute__((aligned(16))) u16 As[3][8192];
  __shared__ __attribute__((aligned(16))) u16 Bs[3][4096];
  const int gx = gridDim.x;
  const int nwg = gx * gridDim.y;
  const int orig = blockIdx.y * gx + blockIdx.x;
  gemm8_body<OUT_BF16>(A, BT, Cp, N, K, gx, nwg, orig, As, Bs);
}

// fused independent up-projections: blocks 0..383 = q-up, 384..895 = kv-up.
__global__ __launch_bounds__(512, 4)
void gemm_up2(const u16* __restrict__ qlat, const u16* __restrict__ WquT, u16* __restrict__ q2,
              const u16* __restrict__ kvl, const u16* __restrict__ WkvuT, u16* __restrict__ kvb) {
  __shared__ __attribute__((aligned(16))) u16 As[3][8192];
  __shared__ __attribute__((aligned(16))) u16 Bs[3][4096];
  int n = blockIdx.x;
  if (n < 384) gemm8_body<1>(qlat, WquT, q2, 3072, 1536, 24, 384, n, As, Bs);
  else         gemm8_body<1>(kvl, WkvuT, kvb, 4096, 512, 32, 512, n - 384, As, Bs);
}

// ---------------- fused norm/split ----------------
__global__ __launch_bounds__(256)
void norm_split(const float* __restrict__ t13, const float* __restrict__ fc, const float* __restrict__ fs,
                u16* __restrict__ qlat, u16* __restrict__ kvl, u16* __restrict__ krope) {
  __shared__ float red[4];
  __shared__ float s_scale;
  int lane = threadIdx.x & 63, wid = threadIdx.x >> 6;
  if (blockIdx.x < 4096) {
    int row = blockIdx.x;
    const float* x = t13 + (size_t)row * 2112;
    float ss = 0.f;
    for (int i = threadIdx.x; i < 1536; i += 256) { float v = x[i]; ss += v * v; }
    ss = waveReduceSum(ss);
    if (lane == 0) red[wid] = ss;
    __syncthreads();
    if (threadIdx.x == 0)
      s_scale = rsqrtf((red[0] + red[1] + red[2] + red[3]) * (1.0f / 1536.0f) + 1e-5f);
    __syncthreads();
    float sc = s_scale;
    u16* o = qlat + (size_t)row * 1536;
    for (int i = threadIdx.x; i < 1536; i += 256) o[i] = f2b(x[i] * sc);
  } else {
    int row = blockIdx.x - 4096;
    int s = row & 2047;
    const float* x = t13 + (size_t)row * 2112 + 1536;
    float ss = 0.f;
    for (int i = threadIdx.x; i < 512; i += 256) { float v = x[i]; ss += v * v; }
    ss = waveReduceSum(ss);
    if (lane == 0) red[wid] = ss;
    __syncthreads();
    if (threadIdx.x == 0)
      s_scale = rsqrtf((red[0] + red[1] + red[2] + red[3]) * (1.0f / 512.0f) + 1e-5f);
    __syncthreads();
    float sc = s_scale;
    for (int i = threadIdx.x; i < 512; i += 256) kvl[(size_t)row * 512 + i] = f2b(x[i] * sc);
    if (threadIdx.x < 32) {
      int i = threadIdx.x;
      float cc = fc[s * 32 + i], sn = fs[s * 32 + i];
      float x0 = x[512 + 2 * i], x1 = x[512 + 2 * i + 1];
      krope[(size_t)row * 64 + 2 * i]     = f2b(x0 * cc - x1 * sn);
      krope[(size_t)row * 64 + 2 * i + 1] = f2b(x0 * sn + x1 * cc);
    }
  }
}

// ---------------- rope + pack Q, PRESCALED by log2e/sqrt(192) ----------------
__global__ __launch_bounds__(256)
void rope_pack_q(const u16* __restrict__ q2, const float* __restrict__ fc, const float* __restrict__ fs,
                 u16* __restrict__ Q) {
  const float scale = 0.10411756711f;  // (1/sqrt(192)) * log2(e)
  int bs = blockIdx.x;
  int b = bs >> 11, s = bs & 2047;
  __shared__ float c[32], sn[32];
  if (threadIdx.x < 32) {
    c[threadIdx.x] = fc[s * 32 + threadIdx.x];
    sn[threadIdx.x] = fs[s * 32 + threadIdx.x];
  }
  __syncthreads();
  const u16* qrow = q2 + (size_t)bs * 3072;
  for (int t = threadIdx.x; t < 512; t += 256) {
    int h = t >> 5, i = t & 31;
    float x0 = b2f(qrow[h * 192 + 128 + 2 * i]);
    float x1 = b2f(qrow[h * 192 + 128 + 2 * i + 1]);
    size_t base = ((size_t)(b * 16 + h) * 2048 + s) * 192;
    Q[base + 2 * i]     = f2b((x0 * c[i] - x1 * sn[i]) * scale);
    Q[base + 2 * i + 1] = f2b((x0 * sn[i] + x1 * c[i]) * scale);
  }
  for (int t = threadIdx.x; t < 2048; t += 256) {
    int h = t >> 7, j = t & 127;
    Q[((size_t)(b * 16 + h) * 2048 + s) * 192 + 64 + j] = f2b(b2f(qrow[h * 192 + j]) * scale);
  }
}

// ---------------- assemble K chunked + V transposed chunked ----------------
__global__ __launch_bounds__(256)
void assemble_kv2(const u16* __restrict__ kvb, const u16* __restrict__ krope,
                  u16* __restrict__ Kc, u16* __restrict__ Vt) {
  int ks = blockIdx.x;   // 0..255
  int bh = blockIdx.y;   // 0..31
  int b = bh >> 4, h = bh & 15;
  int t = threadIdx.x;
  if (t < 192) {
    int kq = t >> 3, sl = t & 7;
    int s = ks * 8 + sl;
    size_t bs = (size_t)(b * 2048 + s);
    uint4 v;
    if (kq < 8) v = *reinterpret_cast<const uint4*>(krope + bs * 64 + kq * 8);
    else        v = *reinterpret_cast<const uint4*>(kvb + bs * 4096 + h * 128 + (kq - 8) * 8);
    *reinterpret_cast<uint4*>(Kc + (((size_t)bh * 24 + kq) * 2048 + s) * 8) = v;
  }
  if (t < 128) {
    int dv = t;
    u16 tmp[8];
    #pragma unroll
    for (int j = 0; j < 8; j++) {
      int s = ks * 8 + j;
      tmp[j] = kvb[(size_t)(b * 2048 + s) * 4096 + 2048 + h * 128 + dv];
    }
    *reinterpret_cast<uint4*>(Vt + (((size_t)bh * 256 + ks) * 128 + dv) * 8) = *reinterpret_cast<uint4*>(tmp);
  }
}

// ---------------- MFMA flash attention v9: joint balanced-pair ----------------
// Pair {tpair, 31-tpair}: ONE key loop to nkB; sub-tile A (small) active while
// k0 < nkA. Each staged K/V tile serves 32 q/wave. v8's staging/vmcnt/barrier
// scheme verbatim. Ps reused sequentially (SM B -> PV B -> SM A -> PV A), wave-
// private. Per-block MFMA work uniform across tpair.
__global__ __launch_bounds__(256, 2)
void flash_attn9(const u16* __restrict__ Q, const u16* __restrict__ Kc,
                 const u16* __restrict__ Vt, u16* __restrict__ O) {
  __shared__ __attribute__((aligned(16))) u16 Ks[2][24 * 64 * 8];  // 49 KB dbuf
  __shared__ __attribute__((aligned(16))) u16 Vs[8 * 128 * 8];     // 16 KB
  __shared__ __attribute__((aligned(16))) u16 Ps[4 * 16 * 72];     // 9 KB per-wave

  const int blk = blockIdx.x;
  const int bh = ((blk & 7) << 2) | (blk >> 7);
  const int tpair = (blk >> 3) & 15;
  const int b = bh >> 4, h = bh & 15;
  const int tid = threadIdx.x, lane = tid & 63, wave = tid >> 6;
  const int quad = lane >> 4, l16 = lane & 15;
  u16* PsW = Ps + wave * 16 * 72;

  const int q0A = tpair * 64;          // small tile: keys < nkA
  const int q0B = (31 - tpair) * 64;   // big tile:  keys < nkB
  const int nkA = q0A + 64;
  const int nkB = q0B + 64;

  bf16x8 onesf;
  #pragma unroll
  for (int j = 0; j < 8; j++) onesf[j] = (l16 == 0) ? (__bf16)1.0f : (__bf16)0.0f;

  auto stageK = [&](u16* KsB, int kk) {
    #pragma unroll
    for (int ii = 0; ii < 6; ii++) {
      int kq = wave * 6 + ii;
      gld16(Kc + (((size_t)bh * 24 + kq) * 2048 + kk + lane) * 8, KsB + kq * 64 * 8);
    }
  };
  auto stageV = [&](int kk) {
    #pragma unroll
    for (int jj = 0; jj < 4; jj++) {
      int vc = wave * 4 + jj, kc = vc >> 1, dvh = vc & 1;
      gld16(Vt + (((size_t)bh * 256 + (kk >> 3) + kc) * 128 + dvh * 64 + lane) * 8,
            Vs + (kc * 128 + dvh * 64) * 8);
    }
  };

  // Q fragments for both sub-tiles (sub 0 = A, sub 1 = B)
  bf16x8 qf[2][6];
  #pragma unroll
  for (int s = 0; s < 2; s++) {
    int qrow = (s ? q0B : q0A) + wave * 16 + l16;
    const u16* qp = Q + ((size_t)bh * 2048 + qrow) * 192 + quad * 8;
    #pragma unroll
    for (int kc = 0; kc < 6; kc++)
      qf[s][kc] = *reinterpret_cast<const bf16x8*>(qp + kc * 32);
  }

  f32x4 zero = {0.f, 0.f, 0.f, 0.f};
  f32x4 oacc[2][9];
  #pragma unroll
  for (int s = 0; s < 2; s++)
    #pragma unroll
    for (int nt = 0; nt < 9; nt++) oacc[s][nt] = zero;

  for (int k0 = 0; k0 < nkB; k0 += 64) {
    const int cur = (k0 >> 6) & 1;
    const bool hasnext = (k0 + 64 < nkB);
    const bool aA = (k0 < nkA);          // block-uniform

    __builtin_amdgcn_s_barrier();        // BAR_a: prev PV (Vs) + prev QK (Ks[cur^1]) done
    __builtin_amdgcn_sched_barrier(0);
    if (k0 == 0) stageK(Ks[0], 0);
    stageV(k0);
    if (hasnext) {
      stageK(Ks[cur ^ 1], k0 + 64);
      asm volatile("s_waitcnt vmcnt(10)" ::: "memory");  // K(cur) done; V+Knext flying
    } else {
      asm volatile("s_waitcnt vmcnt(4)" ::: "memory");   // K(cur) done; V flying
    }
    __builtin_amdgcn_sched_barrier(0);
    __builtin_amdgcn_s_barrier();        // BAR_b: K(cur) visible
    __builtin_amdgcn_sched_barrier(0);

    const u16* KsC = Ks[cur];

    // QK^T: K fragments reused across both sub-tiles when A active
    f32x4 sacc[2][4];
    #pragma unroll
    for (int s = 0; s < 2; s++)
      #pragma unroll
      for (int nt = 0; nt < 4; nt++) sacc[s][nt] = zero;
    if (aA) {
      #pragma unroll
      for (int kc = 0; kc < 6; kc++) {
        #pragma unroll
        for (int nt = 0; nt < 4; nt++) {
          bf16x8 kb = *reinterpret_cast<const bf16x8*>(KsC + ((kc * 4 + quad) * 64 + nt * 16 + l16) * 8);
          sacc[1][nt] = __builtin_amdgcn_mfma_f32_16x16x32_bf16(qf[1][kc], kb, sacc[1][nt], 0, 0, 0);
          sacc[0][nt] = __builtin_amdgcn_mfma_f32_16x16x32_bf16(qf[0][kc], kb, sacc[0][nt], 0, 0, 0);
        }
      }
    } else {
      #pragma unroll
      for (int kc = 0; kc < 6; kc++) {
        #pragma unroll
        for (int nt = 0; nt < 4; nt++) {
          bf16x8 kb = *reinterpret_cast<const bf16x8*>(KsC + ((kc * 4 + quad) * 64 + nt * 16 + l16) * 8);
          sacc[1][nt] = __builtin_amdgcn_mfma_f32_16x16x32_bf16(qf[1][kc], kb, sacc[1][nt], 0, 0, 0);
        }
      }
    }

    // softmax for sub-tile s into PsW (exp2 domain; wave-uniform mask hoist)
    auto softmax = [&](int s, int q0s) {
      if (k0 + 63 <= q0s + wave * 16) {
        #pragma unroll
        for (int r = 0; r < 4; r++)
          #pragma unroll
          for (int nt = 0; nt < 4; nt++) {
            float p = EXP2(sacc[s][nt][r]);
            PsW[(quad * 4 + r) * 72 + nt * 16 + l16] = f2b_hw(p);
          }
      } else {
        #pragma unroll
        for (int r = 0; r < 4; r++) {
          int qrow_g = q0s + wave * 16 + quad * 4 + r;
          #pragma unroll
          for (int nt = 0; nt < 4; nt++) {
            int key = k0 + nt * 16 + l16;
            float e = EXP2(sacc[s][nt][r]);
            float p = (key <= qrow_g) ? e : 0.f;
            PsW[(quad * 4 + r) * 72 + nt * 16 + l16] = f2b_hw(p);
          }
        }
      }
    };
    auto pv = [&](int s) {
      #pragma unroll
      for (int kcp = 0; kcp < 2; kcp++) {
        bf16x8 pa = *reinterpret_cast<const bf16x8*>(PsW + l16 * 72 + kcp * 32 + quad * 8);
        #pragma unroll
        for (int nt = 0; nt < 8; nt++) {
          bf16x8 vb = *reinterpret_cast<const bf16x8*>(Vs + ((kcp * 4 + quad) * 128 + nt * 16 + l16) * 8);
          oacc[s][nt] = __builtin_amdgcn_mfma_f32_16x16x32_bf16(pa, vb, oacc[s][nt], 0, 0, 0);
        }
        oacc[s][8] = __builtin_amdgcn_mfma_f32_16x16x32_bf16(pa, onesf, oacc[s][8], 0, 0, 0);
      }
    };

    softmax(1, q0B);
    if (hasnext) asm volatile("s_waitcnt vmcnt(6)" ::: "memory");  // V done; Knext flying
    else         asm volatile("s_waitcnt vmcnt(0)" ::: "memory");
    __builtin_amdgcn_sched_barrier(0);
    __builtin_amdgcn_s_barrier();        // BAR_c: V(cur) visible
    __builtin_amdgcn_sched_barrier(0);
    pv(1);
    if (aA) {                            // Ps reuse: wave-private, program-ordered
      softmax(0, q0A);
      pv(0);
    }
  }

  // epilogue: both sub-tiles; l at l16==0 of each quad, broadcast within quad
  #pragma unroll
  for (int s = 0; s < 2; s++) {
    int q0s = s ? q0B : q0A;
    #pragma unroll
    for (int r = 0; r < 4; r++) {
      float l = __shfl(oacc[s][8][r], lane & 48, 64);
      float inv = 1.0f / l;
      int sr = q0s + wave * 16 + quad * 4 + r;
      #pragma unroll
      for (int nt = 0; nt < 8; nt++)
        O[((size_t)b * 2048 + sr) * 2048 + h * 128 + nt * 16 + l16] = f2b(oacc[s][nt][r] * inv);
    }
  }
}

// ---------------- launch ----------------
extern "C" void kernel_launch(void* const* d_in, const int* in_sizes, int n_in,
                              void* d_out, int out_size, void* d_ws, size_t ws_size,
                              hipStream_t stream) {
  (void)in_sizes; (void)n_in; (void)out_size; (void)ws_size;
  const float* hs   = (const float*)d_in[0];
  const float* fc   = (const float*)d_in[2];
  const float* fs   = (const float*)d_in[3];
  const float* Wqd  = (const float*)d_in[4];
  const float* Wkvd = (const float*)d_in[5];
  const float* Wqu  = (const float*)d_in[6];
  const float* Wkvu = (const float*)d_in[7];
  const float* Wo   = (const float*)d_in[8];

  char* ws = (char*)d_ws;
  size_t off = 0;
  auto alloc = [&](size_t bytes) { size_t o = off; off += (bytes + 255) & ~(size_t)255; return o; };
  const size_t oHS   = alloc(16777216);  // hs_bf bf16 [4096][2048]
  const size_t oRA   = alloc(16777216);  // Vt bf16 [32][256][128][8]
  const size_t oRB   = alloc(25165824);  // q2 bf16 [4096][3072] -> Kc bf16
  const size_t oRC   = alloc(12582912);  // qlat bf16 [4096][1536]
  const size_t oRD   = alloc(25165824);  // Q bf16 [B*H][S][192]
  const size_t oRE   = alloc(34603008);  // t13 f32 [4096][2112] -> kvb bf16 -> attn_out
  const size_t oKVL  = alloc(4194304);   // kvl bf16 [4096][512]
  const size_t oKR   = alloc(524288);    // krope bf16 [4096][64]
  const size_t oW13T  = alloc(8650752);  // [2112][2048] bf16
  const size_t oWquT  = alloc(9437184);
  const size_t oWkvuT = alloc(4194304);
  const size_t oWoT   = alloc(8388608);

  u16* hs_bf = (u16*)(ws + oHS);
  u16* Vt   = (u16*)(ws + oRA);
  u16* q2   = (u16*)(ws + oRB);
  u16* Kc   = (u16*)(ws + oRB);
  u16* qlat = (u16*)(ws + oRC);
  u16* Qb   = (u16*)(ws + oRD);
  float* t13 = (float*)(ws + oRE);
  u16* kvb  = (u16*)(ws + oRE);
  u16* attn_out = (u16*)(ws + oRE);
  u16* kvl  = (u16*)(ws + oKVL);
  u16* krope = (u16*)(ws + oKR);
  u16* W13T  = (u16*)(ws + oW13T);
  u16* WquT  = (u16*)(ws + oWquT);
  u16* WkvuT = (u16*)(ws + oWkvuT);
  u16* WoT   = (u16*)(ws + oWoT);

  cvt_f32_bf16<<<8192, 256, 0, stream>>>(hs, hs_bf, 2097152);
  transpose_all<<<14976, dim3(32, 8), 0, stream>>>(Wqd, Wkvd, Wqu, Wkvu, Wo, W13T, WquT, WkvuT, WoT);

  // fused down-projections: t13 = hs @ [Wq_down | Wkv_down]
  gemm8<0><<<dim3(17, 16), 512, 0, stream>>>(hs_bf, W13T, t13, 2112, 2048);
  // fused rmsnorm(q-latent) + kv split
  norm_split<<<8192, 256, 0, stream>>>(t13, fc, fs, qlat, kvl, krope);
  // fused independent up-projections (concurrent): q2 and kvb
  gemm_up2<<<896, 512, 0, stream>>>(qlat, WquT, q2, kvl, WkvuT, kvb);
  // rope+pack Q (reads q2 BEFORE Kc overwrites the same buffer in assemble_kv2)
  rope_pack_q<<<4096, 256, 0, stream>>>(q2, fc, fs, Qb);
  assemble_kv2<<<dim3(256, 32), 256, 0, stream>>>(kvb, krope, Kc, Vt);
  // attention v9 (joint balanced-pair)
  flash_attn9<<<dim3(512), 256, 0, stream>>>(Qb, Kc, Vt, attn_out);
  // output projection (fp32 out)
  gemm8<0><<<dim3(16, 16), 512, 0, stream>>>(attn_out, WoT, (float*)d_out, 2048, 2048);
}